// Round 5
// baseline (6386.446 us; speedup 1.0000x reference)
//
#include <hip/hip_runtime.h>
#include <math.h>

// Problem constants
#define TT   240
#define BBATCH 64
#define DDIM 7056
#define NENC 512
#define MHID 256
#define G3   768
#define WRMC 40
#define KWIN 8
#define TOUTC 192
#define RROWS (TOUTC*BBATCH)   // 12288
#define NSTEPS (WRMC + TOUTC)  // 232
#define SBLK 4                 // scan blocks per sample

// ws layout (float offsets). gi is computed for 232 steps only (tail 8 steps of
// the original 240-step region are never written -> safe scratch for hglob/cnt).
#define OFF_GI    ((size_t)0)                        // 232*64*768 = 11403264 used
#define OFF_H2    ((size_t)11403264)                 // 2*64*256 = 32768 (gi tail)
#define OFF_CNT   (OFF_H2 + (size_t)32768)           // 64 uints (gi tail)
#define OFF_Z     ((size_t)11796480)                 // 232*64*512 = 7602176 used
#define OFF_HOPEN OFF_Z                              // 3145728 (reuse after scan)
#define OFF_R1    (OFF_Z + (size_t)3145728)          // 3145728
#define OFF_BTS   (OFF_Z + (size_t)7864320)          // 3276800
#define OFF_GTAB  (OFF_BTS + (size_t)3276800)        // 13824
#define OFF_GBH   OFF_GI                             // reuse gi space for open gh (9437184 < 11403264)

__device__ __forceinline__ float sigmf(float x) { return 1.0f / (1.0f + expf(-x)); }
__device__ __forceinline__ float dot4(float4 a, float4 b) {
  return fmaf(a.x, b.x, fmaf(a.y, b.y, fmaf(a.z, b.z, a.w * b.w)));
}

// C[M,N] = A[M,K] @ W[N,K]^T + bias (optional relu, optional strided out scatter)
__global__ __launch_bounds__(256) void gemm_tn(
    const float* __restrict__ A, const float* __restrict__ W,
    const float* __restrict__ bias, float* __restrict__ C,
    int Mrows, int Ncols, int Kdim, int relu, int outk)
{
  __shared__ float As[16][132];
  __shared__ float Bs[16][132];
  const int tid = threadIdx.x;
  const int bx = blockIdx.x, by = blockIdx.y;
  const int tx = tid & 15, ty = tid >> 4;
  const int lrow = tid >> 2;
  const int lk = (tid & 3) << 2;

  const float* Ab = A + (size_t)by * 128 * Kdim;
  const float* Wb = W + (size_t)bx * 128 * Kdim;

  float c[8][8];
#pragma unroll
  for (int i = 0; i < 8; ++i)
#pragma unroll
    for (int j = 0; j < 8; ++j) c[i][j] = 0.f;

  for (int k0 = 0; k0 < Kdim; k0 += 16) {
    const float4 a0 = *(const float4*)(Ab + (size_t)lrow * Kdim + k0 + lk);
    const float4 a1 = *(const float4*)(Ab + (size_t)(lrow + 64) * Kdim + k0 + lk);
    const float4 b0 = *(const float4*)(Wb + (size_t)lrow * Kdim + k0 + lk);
    const float4 b1 = *(const float4*)(Wb + (size_t)(lrow + 64) * Kdim + k0 + lk);
    __syncthreads();
    As[lk + 0][lrow] = a0.x; As[lk + 1][lrow] = a0.y; As[lk + 2][lrow] = a0.z; As[lk + 3][lrow] = a0.w;
    As[lk + 0][lrow + 64] = a1.x; As[lk + 1][lrow + 64] = a1.y; As[lk + 2][lrow + 64] = a1.z; As[lk + 3][lrow + 64] = a1.w;
    Bs[lk + 0][lrow] = b0.x; Bs[lk + 1][lrow] = b0.y; Bs[lk + 2][lrow] = b0.z; Bs[lk + 3][lrow] = b0.w;
    Bs[lk + 0][lrow + 64] = b1.x; Bs[lk + 1][lrow + 64] = b1.y; Bs[lk + 2][lrow + 64] = b1.z; Bs[lk + 3][lrow + 64] = b1.w;
    __syncthreads();
#pragma unroll
    for (int kk = 0; kk < 16; ++kk) {
      const float4 av0 = *(const float4*)&As[kk][ty * 8];
      const float4 av1 = *(const float4*)&As[kk][ty * 8 + 4];
      const float4 bv0 = *(const float4*)&Bs[kk][tx * 8];
      const float4 bv1 = *(const float4*)&Bs[kk][tx * 8 + 4];
      const float a[8] = {av0.x, av0.y, av0.z, av0.w, av1.x, av1.y, av1.z, av1.w};
      const float b[8] = {bv0.x, bv0.y, bv0.z, bv0.w, bv1.x, bv1.y, bv1.z, bv1.w};
#pragma unroll
      for (int i = 0; i < 8; ++i)
#pragma unroll
        for (int j = 0; j < 8; ++j)
          c[i][j] = fmaf(a[i], b[j], c[i][j]);
    }
  }

  const int n_base = bx * 128 + tx * 8;
  float bj[8];
#pragma unroll
  for (int j = 0; j < 8; ++j) bj[j] = bias ? bias[n_base + j] : 0.f;

#pragma unroll
  for (int i = 0; i < 8; ++i) {
    const int m = by * 128 + ty * 8 + i;
    float o[8];
#pragma unroll
    for (int j = 0; j < 8; ++j) {
      float v = c[i][j] + bj[j];
      if (relu) v = fmaxf(v, 0.f);
      o[j] = v;
    }
    float* dst;
    if (outk >= 0) {
      const int t = m >> 6, b = m & 63;
      dst = C + (((size_t)(t * KWIN + outk) * BBATCH + b) * NENC) + n_base;
    } else {
      dst = C + (size_t)m * Ncols + n_base;
    }
    *(float4*)dst = make_float4(o[0], o[1], o[2], o[3]);
    *(float4*)(dst + 4) = make_float4(o[4], o[5], o[6], o[7]);
  }
}

// gi_table[a][c] = emb[a,:] @ w_ih_c[c,:] + b_ih_c[c]   (18 x 768)
__global__ void gitab_kernel(const float* __restrict__ emb, const float* __restrict__ w_ih_c,
                             const float* __restrict__ b_ih_c, float* __restrict__ gt)
{
  const int idx = blockIdx.x * blockDim.x + threadIdx.x;
  if (idx >= 18 * G3) return;
  const int a = idx / G3, cgate = idx % G3;
  float s = b_ih_c[cgate];
#pragma unroll
  for (int e = 0; e < 32; ++e) s = fmaf(emb[a * 32 + e], w_ih_c[cgate * 32 + e], s);
  gt[idx] = s;
}

// scan3: register-resident weights, 4 blocks per sample, CUB-style flag sync.
// Block p of sample b owns j in [p*64,(p+1)*64) i.e. rows {j, 256+j, 512+j} of w_hh.
// Thread (g = tid>>4, s = tid&15): rows lr = g*6+k (k<6), cols [s*16, s*16+16).
__global__ __launch_bounds__(512, 2) void scan3_kernel(
    const float* __restrict__ gi_all, const float* __restrict__ w_hh,
    const float* __restrict__ b_hh, float* __restrict__ bts,
    float* __restrict__ hglob, unsigned int* __restrict__ cnt)
{
  const int blk = blockIdx.x;
  const int b = blk & 63;
  const int p = blk >> 6;
  const int tid = threadIdx.x;
  const int g = tid >> 4;
  const int s = tid & 15;

  __shared__ __align__(16) float hs[256];
  __shared__ float gacc[192];

  // Weight prologue: 6 rows x 16 cols per thread into registers (96 VGPR).
  float4 w_[6][4];
#pragma unroll
  for (int k = 0; k < 6; ++k) {
    const int lr = g * 6 + k;            // 0..191
    const int gate = lr >> 6;
    const int jj = lr & 63;
    const float* wrow = w_hh + ((size_t)(gate * 256 + p * 64 + jj)) * 256 + s * 16;
#pragma unroll
    for (int q = 0; q < 4; ++q) w_[k][q] = *(const float4*)(wrow + q * 4);
  }

  float bhr = 0.f, bhz = 0.f, bhn = 0.f;
  if (tid < 64) {
    const int j = p * 64 + tid;
    bhr = b_hh[j]; bhz = b_hh[256 + j]; bhn = b_hh[512 + j];
    ((float4*)hs)[tid] = make_float4(0.f, 0.f, 0.f, 0.f);
  }
  __syncthreads();

  for (int t = 0; t < NSTEPS; ++t) {
    float gr = 0.f, gz = 0.f, gn = 0.f;
    if (tid < 64) {
      const float* gp = gi_all + ((size_t)t * BBATCH + b) * G3 + p * 64 + tid;
      gr = gp[0]; gz = gp[256]; gn = gp[512];
    }

    // matvec: part[k] = w_row(g*6+k)[s*16..s*16+16) . h[s*16..)
    const float4 h0 = *(const float4*)&hs[s * 16];
    const float4 h1 = *(const float4*)&hs[s * 16 + 4];
    const float4 h2 = *(const float4*)&hs[s * 16 + 8];
    const float4 h3 = *(const float4*)&hs[s * 16 + 12];
    float part[6];
#pragma unroll
    for (int k = 0; k < 6; ++k)
      part[k] = (dot4(w_[k][0], h0) + dot4(w_[k][1], h1)) +
                (dot4(w_[k][2], h2) + dot4(w_[k][3], h3));
#pragma unroll
    for (int k = 0; k < 6; ++k) {
      float v = part[k];
      v += __shfl_xor(v, 1);
      v += __shfl_xor(v, 2);
      v += __shfl_xor(v, 4);
      v += __shfl_xor(v, 8);
      part[k] = v;
    }
#pragma unroll
    for (int k = 0; k < 6; ++k)
      if (s == k) gacc[g * 6 + k] = part[k];
    __syncthreads();

    // gate combine (first wave), double-buffered h write to global.
    // NOTE: b_hh_n must sit INSIDE the r* product (reference: n = tanh(i_n + r*(Wn.h + b_n)));
    // this being outside was the round-3/4 deterministic 1e-2 failure.
    if (tid < 64) {
      const int j = p * 64 + tid;
      const float r = sigmf(gr + bhr + gacc[tid]);
      const float z = sigmf(gz + bhz + gacc[64 + tid]);
      const float n = tanhf(gn + r * (bhn + gacc[128 + tid]));
      const float hn = (1.f - z) * n + z * hs[j];
      hglob[((size_t)((t + 1) & 1) * BBATCH + b) * 256 + j] = hn;
      if (t >= WRMC) bts[(((size_t)(t - WRMC)) * BBATCH + b) * MHID + j] = hn;
    }
    __syncthreads();   // all h-slice stores issued

    // per-sample 4-block barrier, CUB decoupled-lookback style fencing
    if (tid == 0) {
      __threadfence();  // publish hglob slice before raising the flag
      __hip_atomic_fetch_add(cnt + b, 1u, __ATOMIC_RELAXED, __HIP_MEMORY_SCOPE_AGENT);
      const unsigned int target = (unsigned int)(SBLK * (t + 1));
      while (__hip_atomic_load(cnt + b, __ATOMIC_RELAXED, __HIP_MEMORY_SCOPE_AGENT) < target)
        __builtin_amdgcn_s_sleep(1);
      __threadfence();  // make peers' hglob slices visible
    }
    __syncthreads();

    if (t + 1 < NSTEPS) {
      if (tid < 64)
        ((float4*)hs)[tid] = *(const float4*)(hglob + ((size_t)((t + 1) & 1) * BBATCH + b) * 256 + tid * 4);
      __syncthreads();
    }
  }
}

// Open-loop gate combine: h' from gi_table lookup + gh GEMM result.
__global__ __launch_bounds__(256) void open_gates(
    const float* __restrict__ gtab, const int* __restrict__ act_seq,
    const float* __restrict__ gh, const float* __restrict__ hin,
    float* __restrict__ hout, int kstep)
{
  const int row = blockIdx.x;
  const int j = threadIdx.x;
  const int t = row >> 6, b = row & 63;
  const int a = act_seq[(WRMC + t + kstep) * BBATCH + b];
  const float* gi = gtab + a * G3;
  const float gr = gi[j], gz = gi[256 + j], gn = gi[512 + j];
  const size_t g0 = (size_t)row * G3;
  const float hr = gh[g0 + j], hz = gh[g0 + 256 + j], hnn = gh[g0 + 512 + j];
  const float h = hin[(size_t)row * MHID + j];
  const float r = sigmf(gr + hr);
  const float z = sigmf(gz + hz);
  const float n = tanhf(gn + r * hnn);
  hout[(size_t)row * MHID + j] = (1.f - z) * n + z * h;
}

extern "C" void kernel_launch(void* const* d_in, const int* in_sizes, int n_in,
                              void* d_out, int out_size, void* d_ws, size_t ws_size,
                              hipStream_t stream) {
  const float* obs    = (const float*)d_in[0];
  const int*   act    = (const int*)  d_in[1];
  const float* w_enc  = (const float*)d_in[2];
  const float* b_enc  = (const float*)d_in[3];
  const float* w_ih   = (const float*)d_in[4];
  const float* w_hh   = (const float*)d_in[5];
  const float* b_ih   = (const float*)d_in[6];
  const float* b_hh   = (const float*)d_in[7];
  const float* w_ih_c = (const float*)d_in[8];
  const float* w_hh_c = (const float*)d_in[9];
  const float* b_ih_c = (const float*)d_in[10];
  const float* b_hh_c = (const float*)d_in[11];
  const float* W1     = (const float*)d_in[12];
  const float* b1     = (const float*)d_in[13];
  const float* W2     = (const float*)d_in[14];
  const float* b2     = (const float*)d_in[15];
  const float* emb    = (const float*)d_in[16];

  float* ws  = (float*)d_ws;
  float* out = (float*)d_out;

  float* z     = ws + OFF_Z;
  float* gi    = ws + OFF_GI;
  float* bts   = ws + OFF_BTS;
  float* gtab  = ws + OFF_GTAB;
  float* hopen = ws + OFF_HOPEN;
  float* r1    = ws + OFF_R1;
  float* hglob = ws + OFF_H2;
  unsigned int* cnt = (unsigned int*)(ws + OFF_CNT);
  float* gbh   = ws + OFF_GBH;

  const dim3 blk(256);

  // zero the per-sample sync counters (in-graph; re-runs on every replay)
  hipMemsetAsync(cnt, 0, 64 * sizeof(unsigned int), stream);

  // Phase 1: encoder + input gates, 232 steps only (last 8 never consumed)
  gemm_tn<<<dim3(4, 116), blk, 0, stream>>>(obs, w_enc, b_enc, z, NSTEPS * BBATCH, NENC, DDIM, 0, -1);
  gemm_tn<<<dim3(6, 116), blk, 0, stream>>>(z, w_ih, b_ih, gi, NSTEPS * BBATCH, G3, NENC, 0, -1);
  gitab_kernel<<<54, 256, 0, stream>>>(emb, w_ih_c, b_ih_c, gtab);

  // Phase 2: sequential GRU scan, register-resident weights, 256 blocks
  scan3_kernel<<<SBLK * BBATCH, 512, 0, stream>>>(gi, w_hh, b_hh, bts, hglob, cnt);

  // Phase 3: open-loop rollout, 8 steps over 12288 independent rows
  for (int k = 0; k < KWIN; ++k) {
    const float* hin = (k == 0) ? bts : hopen;
    gemm_tn<<<dim3(6, 96), blk, 0, stream>>>(hin, w_hh_c, b_hh_c, gbh, RROWS, G3, MHID, 0, -1);
    open_gates<<<RROWS, 256, 0, stream>>>(gtab, act, gbh, hin, hopen, k);
    gemm_tn<<<dim3(2, 96), blk, 0, stream>>>(hopen, W1, b1, r1, RROWS, MHID, MHID, 1, -1);
    gemm_tn<<<dim3(4, 96), blk, 0, stream>>>(r1, W2, b2, out, RROWS, NENC, MHID, 0, k);
  }
}

// Round 6
// 2903.656 us; speedup vs baseline: 2.1994x; 2.1994x over previous
//
#include <hip/hip_runtime.h>
#include <math.h>

// Problem constants
#define TT   240
#define BBATCH 64
#define DDIM 7056
#define KENC_PAD 7072          // 7056 padded to %32
#define NENC 512
#define MHID 256
#define G3   768
#define WRMC 40
#define KWIN 8
#define TOUTC 192
#define RROWS (TOUTC*BBATCH)   // 12288
#define NSTEPS (WRMC + TOUTC)  // 232

// ws layout. float offsets unless BOFF_ (bytes). Lifetime-disjoint:
//  [0, 45.61MB)  gi (written by gi-GEMM, read by scan). Early: w_enc split. Phase3: gbh.
//  [45.61,76.02) z (enc out, gi-GEMM in). After scan: wt junk; phase3: hopen,r1.
//  [76.02,89.13) bts (scan out). Early (pre-scan): w_ih split in prefix.
//  [89.13,90.70) w_hh_c/W1/W2 splits.  [90.70,90.76) gtab.   peak 90.76MB <= 91.8 validated.
#define OFF_GI    ((size_t)0)
#define OFF_Z     ((size_t)11403264)
#define OFF_HOPEN OFF_Z
#define OFF_WT    OFF_Z                          // scan-only; hopen overwrites later
#define OFF_R1    (OFF_Z + (size_t)3145728)
#define OFF_BTS   (OFF_Z + (size_t)7602176)      // 19005440
#define OFF_GBH   OFF_GI
#define BOFF_WENC_HI ((size_t)0)                 // in gi region (dead before gi written)
#define BOFF_WENC_LO ((size_t)7243776)           // 512*7072*2
#define BOFF_WIH_HI  ((size_t)19005440*4)        // bts prefix (dead before scan)
#define BOFF_WIH_LO  (BOFF_WIH_HI + (size_t)786432)
#define BOFF_WHHC_HI ((size_t)(19005440+3276800)*4)  // 89128960
#define BOFF_WHHC_LO (BOFF_WHHC_HI + (size_t)393216)
#define BOFF_W1_HI   (BOFF_WHHC_LO + (size_t)393216)
#define BOFF_W1_LO   (BOFF_W1_HI + (size_t)131072)
#define BOFF_W2_HI   (BOFF_W1_LO + (size_t)131072)
#define BOFF_W2_LO   (BOFF_W2_HI + (size_t)262144)
#define OFF_GTAB  ((size_t)((89128960 + 1572864) / 4))   // 22675456

typedef __attribute__((ext_vector_type(8))) short short8v;
typedef __attribute__((ext_vector_type(4))) float f32x4;

__device__ __forceinline__ float sigmf(float x) { return 1.0f / (1.0f + expf(-x)); }
__device__ __forceinline__ float dot4(float4 a, float4 b) {
  return fmaf(a.x, b.x, fmaf(a.y, b.y, fmaf(a.z, b.z, a.w * b.w)));
}
__device__ __forceinline__ unsigned short f2bf(float x) {  // RNE, finite inputs
  unsigned int u = __float_as_uint(x);
  u += 0x7FFFu + ((u >> 16) & 1u);
  return (unsigned short)(u >> 16);
}
__device__ __forceinline__ float bf2f(unsigned short b) {
  return __uint_as_float(((unsigned int)b) << 16);
}

// Split W[N][K] fp32 -> hi/lo bf16 [N][Kpad] (zero-padded)
__global__ void wsplit_kernel(const float* __restrict__ W, short* __restrict__ hi,
                              short* __restrict__ lo, int N, int K, int Kpad) {
  const int idx = blockIdx.x * 256 + threadIdx.x;
  if (idx >= N * Kpad) return;
  const int n = idx / Kpad, k = idx % Kpad;
  const float v = (k < K) ? W[(size_t)n * K + k] : 0.f;
  const unsigned short h = f2bf(v);
  const unsigned short l = f2bf(v - bf2f(h));
  hi[idx] = (short)h; lo[idx] = (short)l;
}

// Split-bf16 MFMA GEMM: C[M,N] = A[M,K]fp32 @ W[N,K]^T (+bias, relu, outk scatter)
// A converted hi/lo in-kernel; W pre-split. 3 MFMA passes ~ fp32 accuracy.
// BM=64, BN=256, BK=32; 256 threads (4 waves), wave w owns cols [w*64, w*64+64).
__global__ __launch_bounds__(256, 2) void gemm_sbf(
    const float* __restrict__ A, const short* __restrict__ Whi, const short* __restrict__ Wlo,
    const float* __restrict__ bias, float* __restrict__ C,
    int M, int N, int K, int Kpad, int relu, int outk)
{
  __shared__ short Ah[64][40], Al[64][40];
  __shared__ short Bh[256][40], Bl[256][40];
  const int tid = threadIdx.x;
  const int bx = blockIdx.x, by = blockIdx.y;
  const int w = tid >> 6;
  const int lane = tid & 63;
  const int l15 = lane & 15;
  const int khalf = (lane >> 4) * 8;

  f32x4 acc[4][4];
#pragma unroll
  for (int i = 0; i < 4; ++i)
#pragma unroll
    for (int j = 0; j < 4; ++j) acc[i][j] = (f32x4){0.f, 0.f, 0.f, 0.f};

  for (int k0 = 0; k0 < Kpad; k0 += 32) {
    __syncthreads();
    // stage A tile (64x32 fp32 -> hi/lo bf16)
#pragma unroll
    for (int u = 0; u < 2; ++u) {
      const int f = tid + u * 256;        // 0..511
      const int row = f >> 3;             // 0..63
      const int kq = (f & 7) * 4;         // 0..28
      float4 v = make_float4(0.f, 0.f, 0.f, 0.f);
      if (k0 + kq < K)                    // K%16==0 -> float4 fully valid or fully pad
        v = *(const float4*)(A + (size_t)(by * 64 + row) * K + k0 + kq);
      const float vv[4] = {v.x, v.y, v.z, v.w};
      short h[4], l[4];
#pragma unroll
      for (int i = 0; i < 4; ++i) {
        const unsigned short hb = f2bf(vv[i]);
        h[i] = (short)hb;
        l[i] = (short)f2bf(vv[i] - bf2f(hb));
      }
      *(short4*)&Ah[row][kq] = make_short4(h[0], h[1], h[2], h[3]);
      *(short4*)&Al[row][kq] = make_short4(l[0], l[1], l[2], l[3]);
    }
    // stage W tiles (pre-split bf16, 2 bufs x 256x32)
#pragma unroll
    for (int u = 0; u < 8; ++u) {
      const int f = tid + u * 256;        // 0..2047
      const int bufsel = f >> 10;
      const int idx = f & 1023;
      const int n = idx >> 2;             // 0..255
      const int kq8 = (idx & 3) * 8;      // 0,8,16,24
      const short* src = (bufsel ? Wlo : Whi) + (size_t)(bx * 256 + n) * Kpad + k0 + kq8;
      const float4 v = *(const float4*)src;
      short* dst = (bufsel ? &Bl[0][0] : &Bh[0][0]) + n * 40 + kq8;
      *(float4*)dst = v;
    }
    __syncthreads();

    short8v ah[4], al[4], bh[4], bl[4];
#pragma unroll
    for (int i = 0; i < 4; ++i) {
      ah[i] = *(short8v*)&Ah[i * 16 + l15][khalf];
      al[i] = *(short8v*)&Al[i * 16 + l15][khalf];
      bh[i] = *(short8v*)&Bh[w * 64 + i * 16 + l15][khalf];
      bl[i] = *(short8v*)&Bl[w * 64 + i * 16 + l15][khalf];
    }
#pragma unroll
    for (int i = 0; i < 4; ++i)
#pragma unroll
      for (int j = 0; j < 4; ++j) {
        acc[i][j] = __builtin_amdgcn_mfma_f32_16x16x32_bf16(ah[i], bh[j], acc[i][j], 0, 0, 0);
        acc[i][j] = __builtin_amdgcn_mfma_f32_16x16x32_bf16(ah[i], bl[j], acc[i][j], 0, 0, 0);
        acc[i][j] = __builtin_amdgcn_mfma_f32_16x16x32_bf16(al[i], bh[j], acc[i][j], 0, 0, 0);
      }
  }

  // epilogue: C row = by*64 + i*16 + (lane>>4)*4 + r ; col = bx*256 + w*64 + j*16 + (lane&15)
  const int r4 = (lane >> 4) * 4;
#pragma unroll
  for (int j = 0; j < 4; ++j) {
    const int col = bx * 256 + w * 64 + j * 16 + l15;
    const float bc = bias ? bias[col] : 0.f;
#pragma unroll
    for (int i = 0; i < 4; ++i) {
      const int mbase = by * 64 + i * 16 + r4;
#pragma unroll
      for (int r = 0; r < 4; ++r) {
        const int m = mbase + r;
        float vv = acc[i][j][r] + bc;
        if (relu) vv = fmaxf(vv, 0.f);
        float* dst;
        if (outk >= 0) {
          const int t = m >> 6, b = m & 63;
          dst = C + (((size_t)(t * KWIN + outk) * BBATCH + b) * NENC) + col;
        } else {
          dst = C + (size_t)m * N + col;
        }
        *dst = vv;
      }
    }
  }
}

// gi_table[a][c] = emb[a,:] @ w_ih_c[c,:] + b_ih_c[c]   (18 x 768)
__global__ void gitab_kernel(const float* __restrict__ emb, const float* __restrict__ w_ih_c,
                             const float* __restrict__ b_ih_c, float* __restrict__ gt)
{
  const int idx = blockIdx.x * blockDim.x + threadIdx.x;
  if (idx >= 18 * G3) return;
  const int a = idx / G3, cgate = idx % G3;
  float s = b_ih_c[cgate];
#pragma unroll
  for (int e = 0; e < 32; ++e) s = fmaf(emb[a * 32 + e], w_ih_c[cgate * 32 + e], s);
  gt[idx] = s;
}

// wt[k][j] = w_hh[j][k]  (k-major transpose, 256 x 768)
__global__ void transpose_whh(const float* __restrict__ w, float* __restrict__ wt) {
  const int id = blockIdx.x * 256 + threadIdx.x;
  const int k = id / G3, j = id % G3;
  wt[id] = w[(size_t)j * MHID + k];
}

// Sequential GRU scan (round-2 validated): one block per sample, 768 threads,
// coalesced k-major weight stream from L2, h broadcast from LDS.
__global__ __launch_bounds__(768) void scan2_kernel(
    const float* __restrict__ gi_all, const float* __restrict__ wt,
    const float* __restrict__ b_hh, float* __restrict__ bts)
{
  const int b = blockIdx.x;
  const int j = threadIdx.x;
  __shared__ float hs[256];
  __shared__ float gacc[768];
  if (j < 256) hs[j] = 0.f;
  const float bj = b_hh[j];
  __syncthreads();

  for (int t = 0; t < NSTEPS; ++t) {
    const float* gi = gi_all + ((size_t)t * BBATCH + b) * G3;
    float gr = 0.f, gz = 0.f, gn = 0.f;
    if (j < 256) { gr = gi[j]; gz = gi[256 + j]; gn = gi[512 + j]; }
    float a0 = bj, a1 = 0.f, a2 = 0.f, a3 = 0.f;
    const float* w = wt + j;
#pragma unroll 8
    for (int k0 = 0; k0 < 256; k0 += 4) {
      const float4 h4 = *(const float4*)&hs[k0];
      a0 = fmaf(w[(size_t)(k0 + 0) * G3], h4.x, a0);
      a1 = fmaf(w[(size_t)(k0 + 1) * G3], h4.y, a1);
      a2 = fmaf(w[(size_t)(k0 + 2) * G3], h4.z, a2);
      a3 = fmaf(w[(size_t)(k0 + 3) * G3], h4.w, a3);
    }
    gacc[j] = (a0 + a1) + (a2 + a3);
    __syncthreads();
    if (j < 256) {
      const float r = sigmf(gr + gacc[j]);
      const float z = sigmf(gz + gacc[256 + j]);
      const float n = tanhf(gn + r * gacc[512 + j]);   // b_hh_n inside r* via gacc init
      const float hn = (1.f - z) * n + z * hs[j];
      hs[j] = hn;
      if (t >= WRMC) bts[(((size_t)(t - WRMC)) * BBATCH + b) * MHID + j] = hn;
    }
    __syncthreads();
  }
}

// Open-loop gate combine
__global__ __launch_bounds__(256) void open_gates(
    const float* __restrict__ gtab, const int* __restrict__ act_seq,
    const float* __restrict__ gh, const float* __restrict__ hin,
    float* __restrict__ hout, int kstep)
{
  const int row = blockIdx.x;
  const int j = threadIdx.x;
  const int t = row >> 6, b = row & 63;
  const int a = act_seq[(WRMC + t + kstep) * BBATCH + b];
  const float* gi = gtab + a * G3;
  const float gr = gi[j], gz = gi[256 + j], gn = gi[512 + j];
  const size_t g0 = (size_t)row * G3;
  const float hr = gh[g0 + j], hz = gh[g0 + 256 + j], hnn = gh[g0 + 512 + j];
  const float h = hin[(size_t)row * MHID + j];
  const float r = sigmf(gr + hr);
  const float z = sigmf(gz + hz);
  const float n = tanhf(gn + r * hnn);
  hout[(size_t)row * MHID + j] = (1.f - z) * n + z * h;
}

extern "C" void kernel_launch(void* const* d_in, const int* in_sizes, int n_in,
                              void* d_out, int out_size, void* d_ws, size_t ws_size,
                              hipStream_t stream) {
  const float* obs    = (const float*)d_in[0];
  const int*   act    = (const int*)  d_in[1];
  const float* w_enc  = (const float*)d_in[2];
  const float* b_enc  = (const float*)d_in[3];
  const float* w_ih   = (const float*)d_in[4];
  const float* w_hh   = (const float*)d_in[5];
  const float* b_ih   = (const float*)d_in[6];
  const float* b_hh   = (const float*)d_in[7];
  const float* w_ih_c = (const float*)d_in[8];
  const float* w_hh_c = (const float*)d_in[9];
  const float* b_ih_c = (const float*)d_in[10];
  const float* b_hh_c = (const float*)d_in[11];
  const float* W1     = (const float*)d_in[12];
  const float* b1     = (const float*)d_in[13];
  const float* W2     = (const float*)d_in[14];
  const float* b2     = (const float*)d_in[15];
  const float* emb    = (const float*)d_in[16];

  float* ws  = (float*)d_ws;
  char*  wsb = (char*)d_ws;
  float* out = (float*)d_out;

  float* z     = ws + OFF_Z;
  float* gi    = ws + OFF_GI;
  float* bts   = ws + OFF_BTS;
  float* gtab  = ws + OFF_GTAB;
  float* hopen = ws + OFF_HOPEN;
  float* r1    = ws + OFF_R1;
  float* wt    = ws + OFF_WT;
  float* gbh   = ws + OFF_GBH;

  short* enc_hi = (short*)(wsb + BOFF_WENC_HI);
  short* enc_lo = (short*)(wsb + BOFF_WENC_LO);
  short* ih_hi  = (short*)(wsb + BOFF_WIH_HI);
  short* ih_lo  = (short*)(wsb + BOFF_WIH_LO);
  short* hhc_hi = (short*)(wsb + BOFF_WHHC_HI);
  short* hhc_lo = (short*)(wsb + BOFF_WHHC_LO);
  short* w1_hi  = (short*)(wsb + BOFF_W1_HI);
  short* w1_lo  = (short*)(wsb + BOFF_W1_LO);
  short* w2_hi  = (short*)(wsb + BOFF_W2_HI);
  short* w2_lo  = (short*)(wsb + BOFF_W2_LO);

  const dim3 blk(256);

  // Weight pre-splits (fp32 -> bf16 hi/lo)
  wsplit_kernel<<<(NENC * KENC_PAD + 255) / 256, blk, 0, stream>>>(w_enc, enc_hi, enc_lo, NENC, DDIM, KENC_PAD);
  wsplit_kernel<<<(G3 * NENC + 255) / 256, blk, 0, stream>>>(w_ih, ih_hi, ih_lo, G3, NENC, NENC);
  wsplit_kernel<<<(G3 * MHID + 255) / 256, blk, 0, stream>>>(w_hh_c, hhc_hi, hhc_lo, G3, MHID, MHID);
  wsplit_kernel<<<(MHID * MHID + 255) / 256, blk, 0, stream>>>(W1, w1_hi, w1_lo, MHID, MHID, MHID);
  wsplit_kernel<<<(NENC * MHID + 255) / 256, blk, 0, stream>>>(W2, w2_hi, w2_lo, NENC, MHID, MHID);
  gitab_kernel<<<54, 256, 0, stream>>>(emb, w_ih_c, b_ih_c, gtab);

  // Phase 1: encoder + input gates (232 steps)
  gemm_sbf<<<dim3(NENC / 256, NSTEPS * BBATCH / 64), blk, 0, stream>>>(
      obs, enc_hi, enc_lo, b_enc, z, NSTEPS * BBATCH, NENC, DDIM, KENC_PAD, 0, -1);
  gemm_sbf<<<dim3(G3 / 256, NSTEPS * BBATCH / 64), blk, 0, stream>>>(
      z, ih_hi, ih_lo, b_ih, gi, NSTEPS * BBATCH, G3, NENC, NENC, 0, -1);

  // Phase 2: sequential GRU scan (weights streamed k-major from L2)
  transpose_whh<<<768, 256, 0, stream>>>(w_hh, wt);
  scan2_kernel<<<BBATCH, 768, 0, stream>>>(gi, wt, b_hh, bts);

  // Phase 3: open-loop rollout
  for (int k = 0; k < KWIN; ++k) {
    const float* hin = (k == 0) ? bts : hopen;
    gemm_sbf<<<dim3(G3 / 256, RROWS / 64), blk, 0, stream>>>(
        hin, hhc_hi, hhc_lo, b_hh_c, gbh, RROWS, G3, MHID, MHID, 0, -1);
    open_gates<<<RROWS, 256, 0, stream>>>(gtab, act, gbh, hin, hopen, k);
    gemm_sbf<<<dim3(MHID / 256, RROWS / 64), blk, 0, stream>>>(
        hopen, w1_hi, w1_lo, b1, r1, RROWS, MHID, MHID, MHID, 1, -1);
    gemm_sbf<<<dim3(NENC / 256, RROWS / 64), blk, 0, stream>>>(
        r1, w2_hi, w2_lo, b2, out, RROWS, NENC, MHID, MHID, 0, k);
  }
}

// Round 7
// 2519.241 us; speedup vs baseline: 2.5351x; 1.1526x over previous
//
#include <hip/hip_runtime.h>
#include <hip/hip_fp16.h>
#include <math.h>

// Problem constants
#define TT   240
#define BBATCH 64
#define DDIM 7056
#define KENC_PAD 7072          // 7056 padded to %32
#define NENC 512
#define MHID 256
#define G3   768
#define WRMC 40
#define KWIN 8
#define TOUTC 192
#define RROWS (TOUTC*BBATCH)   // 12288
#define NSTEPS (WRMC + TOUTC)  // 232

// ws layout. float offsets unless BOFF_ (bytes). Lifetime-disjoint:
//  [0, 45.61MB)  gi (written by gi-GEMM, read by scan). Early: w_enc split. Phase3: gbh.
//  [45.61,76.02) z (enc out, gi-GEMM in). After gi-GEMM: wt2 (fp16). Phase3: hopen,r1.
//  [76.02,89.13) bts (scan out). Early (pre-scan): w_ih split in prefix.
//  [89.13,90.70) w_hh_c/W1/W2 splits.  [90.70,90.76) gtab.   peak 90.76MB <= 91.8 validated.
#define OFF_GI    ((size_t)0)
#define OFF_Z     ((size_t)11403264)
#define OFF_HOPEN OFF_Z
#define OFF_WT    OFF_Z                          // scan-only (fp16 half2); hopen overwrites later
#define OFF_R1    (OFF_Z + (size_t)3145728)
#define OFF_BTS   (OFF_Z + (size_t)7602176)      // 19005440
#define OFF_GBH   OFF_GI
#define BOFF_WENC_HI ((size_t)0)                 // in gi region (dead before gi written)
#define BOFF_WENC_LO ((size_t)7243776)           // 512*7072*2
#define BOFF_WIH_HI  ((size_t)19005440*4)        // bts prefix (dead before scan)
#define BOFF_WIH_LO  (BOFF_WIH_HI + (size_t)786432)
#define BOFF_WHHC_HI ((size_t)(19005440+3276800)*4)  // 89128960
#define BOFF_WHHC_LO (BOFF_WHHC_HI + (size_t)393216)
#define BOFF_W1_HI   (BOFF_WHHC_LO + (size_t)393216)
#define BOFF_W1_LO   (BOFF_W1_HI + (size_t)131072)
#define BOFF_W2_HI   (BOFF_W1_LO + (size_t)131072)
#define BOFF_W2_LO   (BOFF_W2_HI + (size_t)262144)
#define OFF_GTAB  ((size_t)((89128960 + 1572864) / 4))   // 22675456

typedef __attribute__((ext_vector_type(8))) short short8v;
typedef __attribute__((ext_vector_type(4))) float f32x4;

__device__ __forceinline__ float sigmf(float x) { return 1.0f / (1.0f + expf(-x)); }
__device__ __forceinline__ unsigned short f2bf(float x) {  // RNE, finite inputs
  unsigned int u = __float_as_uint(x);
  u += 0x7FFFu + ((u >> 16) & 1u);
  return (unsigned short)(u >> 16);
}
__device__ __forceinline__ float bf2f(unsigned short b) {
  return __uint_as_float(((unsigned int)b) << 16);
}

// Split W[N][K] fp32 -> hi/lo bf16 [N][Kpad] (zero-padded)
__global__ void wsplit_kernel(const float* __restrict__ W, short* __restrict__ hi,
                              short* __restrict__ lo, int N, int K, int Kpad) {
  const int idx = blockIdx.x * 256 + threadIdx.x;
  if (idx >= N * Kpad) return;
  const int n = idx / Kpad, k = idx % Kpad;
  const float v = (k < K) ? W[(size_t)n * K + k] : 0.f;
  const unsigned short h = f2bf(v);
  const unsigned short l = f2bf(v - bf2f(h));
  hi[idx] = (short)h; lo[idx] = (short)l;
}

// Split-bf16 MFMA GEMM: C[M,N] = A[M,K]fp32 @ W[N,K]^T (+bias, relu, outk scatter)
// BM=64, BN=256, BK=32; 256 threads (4 waves), wave w owns cols [w*64, w*64+64).
__global__ __launch_bounds__(256, 2) void gemm_sbf(
    const float* __restrict__ A, const short* __restrict__ Whi, const short* __restrict__ Wlo,
    const float* __restrict__ bias, float* __restrict__ C,
    int M, int N, int K, int Kpad, int relu, int outk)
{
  __shared__ short Ah[64][40], Al[64][40];
  __shared__ short Bh[256][40], Bl[256][40];
  const int tid = threadIdx.x;
  const int bx = blockIdx.x, by = blockIdx.y;
  const int w = tid >> 6;
  const int lane = tid & 63;
  const int l15 = lane & 15;
  const int khalf = (lane >> 4) * 8;

  f32x4 acc[4][4];
#pragma unroll
  for (int i = 0; i < 4; ++i)
#pragma unroll
    for (int j = 0; j < 4; ++j) acc[i][j] = (f32x4){0.f, 0.f, 0.f, 0.f};

  for (int k0 = 0; k0 < Kpad; k0 += 32) {
    __syncthreads();
    // stage A tile (64x32 fp32 -> hi/lo bf16)
#pragma unroll
    for (int u = 0; u < 2; ++u) {
      const int f = tid + u * 256;
      const int row = f >> 3;
      const int kq = (f & 7) * 4;
      float4 v = make_float4(0.f, 0.f, 0.f, 0.f);
      if (k0 + kq < K)
        v = *(const float4*)(A + (size_t)(by * 64 + row) * K + k0 + kq);
      const float vv[4] = {v.x, v.y, v.z, v.w};
      short h[4], l[4];
#pragma unroll
      for (int i = 0; i < 4; ++i) {
        const unsigned short hb = f2bf(vv[i]);
        h[i] = (short)hb;
        l[i] = (short)f2bf(vv[i] - bf2f(hb));
      }
      *(short4*)&Ah[row][kq] = make_short4(h[0], h[1], h[2], h[3]);
      *(short4*)&Al[row][kq] = make_short4(l[0], l[1], l[2], l[3]);
    }
    // stage W tiles (pre-split bf16, 2 bufs x 256x32)
#pragma unroll
    for (int u = 0; u < 8; ++u) {
      const int f = tid + u * 256;
      const int bufsel = f >> 10;
      const int idx = f & 1023;
      const int n = idx >> 2;
      const int kq8 = (idx & 3) * 8;
      const short* src = (bufsel ? Wlo : Whi) + (size_t)(bx * 256 + n) * Kpad + k0 + kq8;
      const float4 v = *(const float4*)src;
      short* dst = (bufsel ? &Bl[0][0] : &Bh[0][0]) + n * 40 + kq8;
      *(float4*)dst = v;
    }
    __syncthreads();

    short8v ah[4], al[4], bh[4], bl[4];
#pragma unroll
    for (int i = 0; i < 4; ++i) {
      ah[i] = *(short8v*)&Ah[i * 16 + l15][khalf];
      al[i] = *(short8v*)&Al[i * 16 + l15][khalf];
      bh[i] = *(short8v*)&Bh[w * 64 + i * 16 + l15][khalf];
      bl[i] = *(short8v*)&Bl[w * 64 + i * 16 + l15][khalf];
    }
#pragma unroll
    for (int i = 0; i < 4; ++i)
#pragma unroll
      for (int j = 0; j < 4; ++j) {
        acc[i][j] = __builtin_amdgcn_mfma_f32_16x16x32_bf16(ah[i], bh[j], acc[i][j], 0, 0, 0);
        acc[i][j] = __builtin_amdgcn_mfma_f32_16x16x32_bf16(ah[i], bl[j], acc[i][j], 0, 0, 0);
        acc[i][j] = __builtin_amdgcn_mfma_f32_16x16x32_bf16(al[i], bh[j], acc[i][j], 0, 0, 0);
      }
  }

  const int r4 = (lane >> 4) * 4;
#pragma unroll
  for (int j = 0; j < 4; ++j) {
    const int col = bx * 256 + w * 64 + j * 16 + l15;
    const float bc = bias ? bias[col] : 0.f;
#pragma unroll
    for (int i = 0; i < 4; ++i) {
      const int mbase = by * 64 + i * 16 + r4;
#pragma unroll
      for (int r = 0; r < 4; ++r) {
        const int m = mbase + r;
        float vv = acc[i][j][r] + bc;
        if (relu) vv = fmaxf(vv, 0.f);
        float* dst;
        if (outk >= 0) {
          const int t = m >> 6, b = m & 63;
          dst = C + (((size_t)(t * KWIN + outk) * BBATCH + b) * NENC) + col;
        } else {
          dst = C + (size_t)m * N + col;
        }
        *dst = vv;
      }
    }
  }
}

// gi_table[a][c] = emb[a,:] @ w_ih_c[c,:] + b_ih_c[c]   (18 x 768)
__global__ void gitab_kernel(const float* __restrict__ emb, const float* __restrict__ w_ih_c,
                             const float* __restrict__ b_ih_c, float* __restrict__ gt)
{
  const int idx = blockIdx.x * blockDim.x + threadIdx.x;
  if (idx >= 18 * G3) return;
  const int a = idx / G3, cgate = idx % G3;
  float s = b_ih_c[cgate];
#pragma unroll
  for (int e = 0; e < 32; ++e) s = fmaf(emb[a * 32 + e], w_ih_c[cgate * 32 + e], s);
  gt[idx] = s;
}

// wt2[p][j] = half2(w_hh[j][2p], w_hh[j][2p+1])  -- fp16 k-pair-packed transpose.
// fp16 is safe here: |w_hh| <= 1/16 so rel err ~2^-12 (8x tighter than bf16).
__global__ void transpose_whh_h2(const float* __restrict__ w, __half2* __restrict__ wt2) {
  const int id = blockIdx.x * 256 + threadIdx.x;   // 0..98303
  if (id >= 128 * G3) return;
  const int p = id / G3, j = id % G3;
  const float w0 = w[(size_t)j * MHID + 2 * p];
  const float w1 = w[(size_t)j * MHID + 2 * p + 1];
  wt2[id] = __floats2half2_rn(w0, w1);
}

// Sequential GRU scan: one block per sample, 768 threads, fp16 weight stream
// (half the bytes of round-6's fp32 stream; per-CU L2 stream is the bound).
__global__ __launch_bounds__(768) void scan2_kernel(
    const float* __restrict__ gi_all, const __half2* __restrict__ wt2,
    const float* __restrict__ b_hh, float* __restrict__ bts)
{
  const int b = blockIdx.x;
  const int j = threadIdx.x;
  __shared__ float hs[256];
  __shared__ float gacc[768];
  if (j < 256) hs[j] = 0.f;
  const float bj = b_hh[j];
  __syncthreads();

  for (int t = 0; t < NSTEPS; ++t) {
    const float* gi = gi_all + ((size_t)t * BBATCH + b) * G3;
    float gr = 0.f, gz = 0.f, gn = 0.f;
    if (j < 256) { gr = gi[j]; gz = gi[256 + j]; gn = gi[512 + j]; }
    float a0 = bj, a1 = 0.f, a2 = 0.f, a3 = 0.f;
    const __half2* w = wt2 + j;
#pragma unroll 8
    for (int p = 0; p < 128; p += 2) {
      const float4 h4 = *(const float4*)&hs[p * 2];
      const float2 wa = __half22float2(w[(size_t)p * G3]);
      const float2 wb = __half22float2(w[(size_t)(p + 1) * G3]);
      a0 = fmaf(wa.x, h4.x, a0);
      a1 = fmaf(wa.y, h4.y, a1);
      a2 = fmaf(wb.x, h4.z, a2);
      a3 = fmaf(wb.y, h4.w, a3);
    }
    gacc[j] = (a0 + a1) + (a2 + a3);
    __syncthreads();
    if (j < 256) {
      const float r = sigmf(gr + gacc[j]);
      const float z = sigmf(gz + gacc[256 + j]);
      const float n = tanhf(gn + r * gacc[512 + j]);   // b_hh_n inside r* via gacc init
      const float hn = (1.f - z) * n + z * hs[j];
      hs[j] = hn;
      if (t >= WRMC) bts[(((size_t)(t - WRMC)) * BBATCH + b) * MHID + j] = hn;
    }
    __syncthreads();
  }
}

// Open-loop gate combine
__global__ __launch_bounds__(256) void open_gates(
    const float* __restrict__ gtab, const int* __restrict__ act_seq,
    const float* __restrict__ gh, const float* __restrict__ hin,
    float* __restrict__ hout, int kstep)
{
  const int row = blockIdx.x;
  const int j = threadIdx.x;
  const int t = row >> 6, b = row & 63;
  const int a = act_seq[(WRMC + t + kstep) * BBATCH + b];
  const float* gi = gtab + a * G3;
  const float gr = gi[j], gz = gi[256 + j], gn = gi[512 + j];
  const size_t g0 = (size_t)row * G3;
  const float hr = gh[g0 + j], hz = gh[g0 + 256 + j], hnn = gh[g0 + 512 + j];
  const float h = hin[(size_t)row * MHID + j];
  const float r = sigmf(gr + hr);
  const float z = sigmf(gz + hz);
  const float n = tanhf(gn + r * hnn);
  hout[(size_t)row * MHID + j] = (1.f - z) * n + z * h;
}

extern "C" void kernel_launch(void* const* d_in, const int* in_sizes, int n_in,
                              void* d_out, int out_size, void* d_ws, size_t ws_size,
                              hipStream_t stream) {
  const float* obs    = (const float*)d_in[0];
  const int*   act    = (const int*)  d_in[1];
  const float* w_enc  = (const float*)d_in[2];
  const float* b_enc  = (const float*)d_in[3];
  const float* w_ih   = (const float*)d_in[4];
  const float* w_hh   = (const float*)d_in[5];
  const float* b_ih   = (const float*)d_in[6];
  const float* b_hh   = (const float*)d_in[7];
  const float* w_ih_c = (const float*)d_in[8];
  const float* w_hh_c = (const float*)d_in[9];
  const float* b_ih_c = (const float*)d_in[10];
  const float* b_hh_c = (const float*)d_in[11];
  const float* W1     = (const float*)d_in[12];
  const float* b1     = (const float*)d_in[13];
  const float* W2     = (const float*)d_in[14];
  const float* b2     = (const float*)d_in[15];
  const float* emb    = (const float*)d_in[16];

  float* ws  = (float*)d_ws;
  char*  wsb = (char*)d_ws;
  float* out = (float*)d_out;

  float* z     = ws + OFF_Z;
  float* gi    = ws + OFF_GI;
  float* bts   = ws + OFF_BTS;
  float* gtab  = ws + OFF_GTAB;
  float* hopen = ws + OFF_HOPEN;
  float* r1    = ws + OFF_R1;
  __half2* wt2 = (__half2*)(ws + OFF_WT);
  float* gbh   = ws + OFF_GBH;

  short* enc_hi = (short*)(wsb + BOFF_WENC_HI);
  short* enc_lo = (short*)(wsb + BOFF_WENC_LO);
  short* ih_hi  = (short*)(wsb + BOFF_WIH_HI);
  short* ih_lo  = (short*)(wsb + BOFF_WIH_LO);
  short* hhc_hi = (short*)(wsb + BOFF_WHHC_HI);
  short* hhc_lo = (short*)(wsb + BOFF_WHHC_LO);
  short* w1_hi  = (short*)(wsb + BOFF_W1_HI);
  short* w1_lo  = (short*)(wsb + BOFF_W1_LO);
  short* w2_hi  = (short*)(wsb + BOFF_W2_HI);
  short* w2_lo  = (short*)(wsb + BOFF_W2_LO);

  const dim3 blk(256);

  // Weight pre-splits (fp32 -> bf16 hi/lo)
  wsplit_kernel<<<(NENC * KENC_PAD + 255) / 256, blk, 0, stream>>>(w_enc, enc_hi, enc_lo, NENC, DDIM, KENC_PAD);
  wsplit_kernel<<<(G3 * NENC + 255) / 256, blk, 0, stream>>>(w_ih, ih_hi, ih_lo, G3, NENC, NENC);
  wsplit_kernel<<<(G3 * MHID + 255) / 256, blk, 0, stream>>>(w_hh_c, hhc_hi, hhc_lo, G3, MHID, MHID);
  wsplit_kernel<<<(MHID * MHID + 255) / 256, blk, 0, stream>>>(W1, w1_hi, w1_lo, MHID, MHID, MHID);
  wsplit_kernel<<<(NENC * MHID + 255) / 256, blk, 0, stream>>>(W2, w2_hi, w2_lo, NENC, MHID, MHID);
  gitab_kernel<<<54, 256, 0, stream>>>(emb, w_ih_c, b_ih_c, gtab);

  // Phase 1: encoder + input gates (232 steps)
  gemm_sbf<<<dim3(NENC / 256, NSTEPS * BBATCH / 64), blk, 0, stream>>>(
      obs, enc_hi, enc_lo, b_enc, z, NSTEPS * BBATCH, NENC, DDIM, KENC_PAD, 0, -1);
  gemm_sbf<<<dim3(G3 / 256, NSTEPS * BBATCH / 64), blk, 0, stream>>>(
      z, ih_hi, ih_lo, b_ih, gi, NSTEPS * BBATCH, G3, NENC, NENC, 0, -1);

  // Phase 2: sequential GRU scan (fp16 weights streamed k-major from L2)
  transpose_whh_h2<<<(128 * G3 + 255) / 256, blk, 0, stream>>>(w_hh, wt2);
  scan2_kernel<<<BBATCH, 768, 0, stream>>>(gi, wt2, b_hh, bts);

  // Phase 3: open-loop rollout
  for (int k = 0; k < KWIN; ++k) {
    const float* hin = (k == 0) ? bts : hopen;
    gemm_sbf<<<dim3(G3 / 256, RROWS / 64), blk, 0, stream>>>(
        hin, hhc_hi, hhc_lo, b_hh_c, gbh, RROWS, G3, MHID, MHID, 0, -1);
    open_gates<<<RROWS, 256, 0, stream>>>(gtab, act, gbh, hin, hopen, k);
    gemm_sbf<<<dim3(MHID / 256, RROWS / 64), blk, 0, stream>>>(
        hopen, w1_hi, w1_lo, b1, r1, RROWS, MHID, MHID, MHID, 1, -1);
    gemm_sbf<<<dim3(NENC / 256, RROWS / 64), blk, 0, stream>>>(
        r1, w2_hi, w2_lo, b2, out, RROWS, NENC, MHID, MHID, 0, k);
  }
}

// Round 8
// 2257.422 us; speedup vs baseline: 2.8291x; 1.1160x over previous
//
#include <hip/hip_runtime.h>
#include <hip/hip_fp16.h>
#include <math.h>

// Problem constants
#define TT   240
#define BBATCH 64
#define DDIM 7056
#define KENC_PAD 7072          // 7056 padded to %32
#define NENC 512
#define MHID 256
#define G3   768
#define WRMC 40
#define KWIN 8
#define TOUTC 192
#define RROWS (TOUTC*BBATCH)   // 12288
#define NSTEPS (WRMC + TOUTC)  // 232

// ws layout. float offsets unless BOFF_ (bytes). Lifetime-disjoint (validated r6/r7):
#define OFF_GI    ((size_t)0)
#define OFF_Z     ((size_t)11403264)
#define OFF_HOPEN OFF_Z
#define OFF_WT    OFF_Z                          // scan-only (fp16 packed); hopen overwrites later
#define OFF_R1    (OFF_Z + (size_t)3145728)
#define OFF_BTS   (OFF_Z + (size_t)7602176)      // 19005440
#define OFF_GBH   OFF_GI
#define BOFF_WENC_HI ((size_t)0)                 // in gi region (dead before gi written)
#define BOFF_WENC_LO ((size_t)7243776)           // 512*7072*2
#define BOFF_WIH_HI  ((size_t)19005440*4)        // bts prefix (dead before scan)
#define BOFF_WIH_LO  (BOFF_WIH_HI + (size_t)786432)
#define BOFF_WHHC_HI ((size_t)(19005440+3276800)*4)  // 89128960
#define BOFF_WHHC_LO (BOFF_WHHC_HI + (size_t)393216)
#define BOFF_W1_HI   (BOFF_WHHC_LO + (size_t)393216)
#define BOFF_W1_LO   (BOFF_W1_HI + (size_t)131072)
#define BOFF_W2_HI   (BOFF_W1_LO + (size_t)131072)
#define BOFF_W2_LO   (BOFF_W2_HI + (size_t)262144)
#define OFF_GTAB  ((size_t)((89128960 + 1572864) / 4))   // 22675456

typedef __attribute__((ext_vector_type(8))) short short8v;
typedef __attribute__((ext_vector_type(4))) float f32x4;

__device__ __forceinline__ float sigmf(float x) { return 1.0f / (1.0f + expf(-x)); }
__device__ __forceinline__ unsigned short f2bf(float x) {  // RNE, finite inputs
  unsigned int u = __float_as_uint(x);
  u += 0x7FFFu + ((u >> 16) & 1u);
  return (unsigned short)(u >> 16);
}
__device__ __forceinline__ float bf2f(unsigned short b) {
  return __uint_as_float(((unsigned int)b) << 16);
}

// Split W[N][K] fp32 -> hi/lo bf16 [N][Kpad] (zero-padded)
__global__ void wsplit_kernel(const float* __restrict__ W, short* __restrict__ hi,
                              short* __restrict__ lo, int N, int K, int Kpad) {
  const int idx = blockIdx.x * 256 + threadIdx.x;
  if (idx >= N * Kpad) return;
  const int n = idx / Kpad, k = idx % Kpad;
  const float v = (k < K) ? W[(size_t)n * K + k] : 0.f;
  const unsigned short h = f2bf(v);
  const unsigned short l = f2bf(v - bf2f(h));
  hi[idx] = (short)h; lo[idx] = (short)l;
}

// Split-bf16 MFMA GEMM: C[M,N] = A[M,K]fp32 @ W[N,K]^T (+bias, relu, outk scatter)
// BM=64, BN=256, BK=32; 256 threads (4 waves), wave w owns cols [w*64, w*64+64).
__global__ __launch_bounds__(256, 2) void gemm_sbf(
    const float* __restrict__ A, const short* __restrict__ Whi, const short* __restrict__ Wlo,
    const float* __restrict__ bias, float* __restrict__ C,
    int M, int N, int K, int Kpad, int relu, int outk)
{
  __shared__ short Ah[64][40], Al[64][40];
  __shared__ short Bh[256][40], Bl[256][40];
  const int tid = threadIdx.x;
  const int bx = blockIdx.x, by = blockIdx.y;
  const int w = tid >> 6;
  const int lane = tid & 63;
  const int l15 = lane & 15;
  const int khalf = (lane >> 4) * 8;

  f32x4 acc[4][4];
#pragma unroll
  for (int i = 0; i < 4; ++i)
#pragma unroll
    for (int j = 0; j < 4; ++j) acc[i][j] = (f32x4){0.f, 0.f, 0.f, 0.f};

  for (int k0 = 0; k0 < Kpad; k0 += 32) {
    __syncthreads();
#pragma unroll
    for (int u = 0; u < 2; ++u) {
      const int f = tid + u * 256;
      const int row = f >> 3;
      const int kq = (f & 7) * 4;
      float4 v = make_float4(0.f, 0.f, 0.f, 0.f);
      if (k0 + kq < K)
        v = *(const float4*)(A + (size_t)(by * 64 + row) * K + k0 + kq);
      const float vv[4] = {v.x, v.y, v.z, v.w};
      short h[4], l[4];
#pragma unroll
      for (int i = 0; i < 4; ++i) {
        const unsigned short hb = f2bf(vv[i]);
        h[i] = (short)hb;
        l[i] = (short)f2bf(vv[i] - bf2f(hb));
      }
      *(short4*)&Ah[row][kq] = make_short4(h[0], h[1], h[2], h[3]);
      *(short4*)&Al[row][kq] = make_short4(l[0], l[1], l[2], l[3]);
    }
#pragma unroll
    for (int u = 0; u < 8; ++u) {
      const int f = tid + u * 256;
      const int bufsel = f >> 10;
      const int idx = f & 1023;
      const int n = idx >> 2;
      const int kq8 = (idx & 3) * 8;
      const short* src = (bufsel ? Wlo : Whi) + (size_t)(bx * 256 + n) * Kpad + k0 + kq8;
      const float4 v = *(const float4*)src;
      short* dst = (bufsel ? &Bl[0][0] : &Bh[0][0]) + n * 40 + kq8;
      *(float4*)dst = v;
    }
    __syncthreads();

    short8v ah[4], al[4], bh[4], bl[4];
#pragma unroll
    for (int i = 0; i < 4; ++i) {
      ah[i] = *(short8v*)&Ah[i * 16 + l15][khalf];
      al[i] = *(short8v*)&Al[i * 16 + l15][khalf];
      bh[i] = *(short8v*)&Bh[w * 64 + i * 16 + l15][khalf];
      bl[i] = *(short8v*)&Bl[w * 64 + i * 16 + l15][khalf];
    }
#pragma unroll
    for (int i = 0; i < 4; ++i)
#pragma unroll
      for (int j = 0; j < 4; ++j) {
        acc[i][j] = __builtin_amdgcn_mfma_f32_16x16x32_bf16(ah[i], bh[j], acc[i][j], 0, 0, 0);
        acc[i][j] = __builtin_amdgcn_mfma_f32_16x16x32_bf16(ah[i], bl[j], acc[i][j], 0, 0, 0);
        acc[i][j] = __builtin_amdgcn_mfma_f32_16x16x32_bf16(al[i], bh[j], acc[i][j], 0, 0, 0);
      }
  }

  const int r4 = (lane >> 4) * 4;
#pragma unroll
  for (int j = 0; j < 4; ++j) {
    const int col = bx * 256 + w * 64 + j * 16 + l15;
    const float bc = bias ? bias[col] : 0.f;
#pragma unroll
    for (int i = 0; i < 4; ++i) {
      const int mbase = by * 64 + i * 16 + r4;
#pragma unroll
      for (int r = 0; r < 4; ++r) {
        const int m = mbase + r;
        float vv = acc[i][j][r] + bc;
        if (relu) vv = fmaxf(vv, 0.f);
        float* dst;
        if (outk >= 0) {
          const int t = m >> 6, b = m & 63;
          dst = C + (((size_t)(t * KWIN + outk) * BBATCH + b) * NENC) + col;
        } else {
          dst = C + (size_t)m * N + col;
        }
        *dst = vv;
      }
    }
  }
}

// gi_table[a][c] = emb[a,:] @ w_ih_c[c,:] + b_ih_c[c]   (18 x 768)
__global__ void gitab_kernel(const float* __restrict__ emb, const float* __restrict__ w_ih_c,
                             const float* __restrict__ b_ih_c, float* __restrict__ gt)
{
  const int idx = blockIdx.x * blockDim.x + threadIdx.x;
  if (idx >= 18 * G3) return;
  const int a = idx / G3, cgate = idx % G3;
  float s = b_ih_c[cgate];
#pragma unroll
  for (int e = 0; e < 32; ++e) s = fmaf(emb[a * 32 + e], w_ih_c[cgate * 32 + e], s);
  gt[idx] = s;
}

// wt8 packing: wt8[k8][j] = float4 holding 8 fp16 = w_hh[j][k8*8 .. k8*8+7].
// One 16B load per 8 k-values in the scan; lane-consecutive j -> coalesced.
__global__ void transpose_whh_p8(const float* __restrict__ w, float4* __restrict__ wt8) {
  const int id = blockIdx.x * 256 + threadIdx.x;   // 0..24575
  if (id >= 32 * G3) return;
  const int k8 = id / G3, j = id % G3;
  const float* src = w + (size_t)j * MHID + k8 * 8;
  __half2 h2[4];
#pragma unroll
  for (int q = 0; q < 4; ++q)
    h2[q] = __floats2half2_rn(src[2 * q], src[2 * q + 1]);
  wt8[id] = *(float4*)h2;
}

// Sequential GRU scan: one block per sample, 768 threads, fp16 weight stream
// packed 8-per-load (16B float4) -> 8x fewer load instructions than round 7.
__global__ __launch_bounds__(768) void scan2_kernel(
    const float* __restrict__ gi_all, const float4* __restrict__ wt8,
    const float* __restrict__ b_hh, float* __restrict__ bts)
{
  const int b = blockIdx.x;
  const int j = threadIdx.x;
  __shared__ __align__(16) float hs[256];
  __shared__ float gacc[768];
  if (j < 256) hs[j] = 0.f;
  const float bj = b_hh[j];
  __syncthreads();

  const float4* hs4 = (const float4*)hs;

  for (int t = 0; t < NSTEPS; ++t) {
    const float* gi = gi_all + ((size_t)t * BBATCH + b) * G3;
    float gr = 0.f, gz = 0.f, gn = 0.f;
    if (j < 256) { gr = gi[j]; gz = gi[256 + j]; gn = gi[512 + j]; }
    float a0 = bj, a1 = 0.f, a2 = 0.f, a3 = 0.f;
#pragma unroll 4
    for (int k8 = 0; k8 < 32; ++k8) {
      const float4 raw = wt8[(size_t)k8 * G3 + j];
      const __half2* hw = (const __half2*)&raw;
      const float2 f0 = __half22float2(hw[0]);
      const float2 f1 = __half22float2(hw[1]);
      const float2 f2 = __half22float2(hw[2]);
      const float2 f3 = __half22float2(hw[3]);
      const float4 ha = hs4[k8 * 2];
      const float4 hb = hs4[k8 * 2 + 1];
      a0 = fmaf(f0.x, ha.x, a0); a1 = fmaf(f0.y, ha.y, a1);
      a2 = fmaf(f1.x, ha.z, a2); a3 = fmaf(f1.y, ha.w, a3);
      a0 = fmaf(f2.x, hb.x, a0); a1 = fmaf(f2.y, hb.y, a1);
      a2 = fmaf(f3.x, hb.z, a2); a3 = fmaf(f3.y, hb.w, a3);
    }
    gacc[j] = (a0 + a1) + (a2 + a3);
    __syncthreads();
    if (j < 256) {
      const float r = sigmf(gr + gacc[j]);
      const float z = sigmf(gz + gacc[256 + j]);
      const float n = tanhf(gn + r * gacc[512 + j]);   // b_hh_n inside r* via gacc init
      const float hn = (1.f - z) * n + z * hs[j];
      hs[j] = hn;
      if (t >= WRMC) bts[(((size_t)(t - WRMC)) * BBATCH + b) * MHID + j] = hn;
    }
    __syncthreads();
  }
}

// Open-loop gate combine
__global__ __launch_bounds__(256) void open_gates(
    const float* __restrict__ gtab, const int* __restrict__ act_seq,
    const float* __restrict__ gh, const float* __restrict__ hin,
    float* __restrict__ hout, int kstep)
{
  const int row = blockIdx.x;
  const int j = threadIdx.x;
  const int t = row >> 6, b = row & 63;
  const int a = act_seq[(WRMC + t + kstep) * BBATCH + b];
  const float* gi = gtab + a * G3;
  const float gr = gi[j], gz = gi[256 + j], gn = gi[512 + j];
  const size_t g0 = (size_t)row * G3;
  const float hr = gh[g0 + j], hz = gh[g0 + 256 + j], hnn = gh[g0 + 512 + j];
  const float h = hin[(size_t)row * MHID + j];
  const float r = sigmf(gr + hr);
  const float z = sigmf(gz + hz);
  const float n = tanhf(gn + r * hnn);
  hout[(size_t)row * MHID + j] = (1.f - z) * n + z * h;
}

extern "C" void kernel_launch(void* const* d_in, const int* in_sizes, int n_in,
                              void* d_out, int out_size, void* d_ws, size_t ws_size,
                              hipStream_t stream) {
  const float* obs    = (const float*)d_in[0];
  const int*   act    = (const int*)  d_in[1];
  const float* w_enc  = (const float*)d_in[2];
  const float* b_enc  = (const float*)d_in[3];
  const float* w_ih   = (const float*)d_in[4];
  const float* w_hh   = (const float*)d_in[5];
  const float* b_ih   = (const float*)d_in[6];
  const float* b_hh   = (const float*)d_in[7];
  const float* w_ih_c = (const float*)d_in[8];
  const float* w_hh_c = (const float*)d_in[9];
  const float* b_ih_c = (const float*)d_in[10];
  const float* b_hh_c = (const float*)d_in[11];
  const float* W1     = (const float*)d_in[12];
  const float* b1     = (const float*)d_in[13];
  const float* W2     = (const float*)d_in[14];
  const float* b2     = (const float*)d_in[15];
  const float* emb    = (const float*)d_in[16];

  float* ws  = (float*)d_ws;
  char*  wsb = (char*)d_ws;
  float* out = (float*)d_out;

  float* z     = ws + OFF_Z;
  float* gi    = ws + OFF_GI;
  float* bts   = ws + OFF_BTS;
  float* gtab  = ws + OFF_GTAB;
  float* hopen = ws + OFF_HOPEN;
  float* r1    = ws + OFF_R1;
  float4* wt8  = (float4*)(ws + OFF_WT);
  float* gbh   = ws + OFF_GBH;

  short* enc_hi = (short*)(wsb + BOFF_WENC_HI);
  short* enc_lo = (short*)(wsb + BOFF_WENC_LO);
  short* ih_hi  = (short*)(wsb + BOFF_WIH_HI);
  short* ih_lo  = (short*)(wsb + BOFF_WIH_LO);
  short* hhc_hi = (short*)(wsb + BOFF_WHHC_HI);
  short* hhc_lo = (short*)(wsb + BOFF_WHHC_LO);
  short* w1_hi  = (short*)(wsb + BOFF_W1_HI);
  short* w1_lo  = (short*)(wsb + BOFF_W1_LO);
  short* w2_hi  = (short*)(wsb + BOFF_W2_HI);
  short* w2_lo  = (short*)(wsb + BOFF_W2_LO);

  const dim3 blk(256);

  // Weight pre-splits (fp32 -> bf16 hi/lo)
  wsplit_kernel<<<(NENC * KENC_PAD + 255) / 256, blk, 0, stream>>>(w_enc, enc_hi, enc_lo, NENC, DDIM, KENC_PAD);
  wsplit_kernel<<<(G3 * NENC + 255) / 256, blk, 0, stream>>>(w_ih, ih_hi, ih_lo, G3, NENC, NENC);
  wsplit_kernel<<<(G3 * MHID + 255) / 256, blk, 0, stream>>>(w_hh_c, hhc_hi, hhc_lo, G3, MHID, MHID);
  wsplit_kernel<<<(MHID * MHID + 255) / 256, blk, 0, stream>>>(W1, w1_hi, w1_lo, MHID, MHID, MHID);
  wsplit_kernel<<<(NENC * MHID + 255) / 256, blk, 0, stream>>>(W2, w2_hi, w2_lo, NENC, MHID, MHID);
  gitab_kernel<<<54, 256, 0, stream>>>(emb, w_ih_c, b_ih_c, gtab);

  // Phase 1: encoder + input gates (232 steps)
  gemm_sbf<<<dim3(NENC / 256, NSTEPS * BBATCH / 64), blk, 0, stream>>>(
      obs, enc_hi, enc_lo, b_enc, z, NSTEPS * BBATCH, NENC, DDIM, KENC_PAD, 0, -1);
  gemm_sbf<<<dim3(G3 / 256, NSTEPS * BBATCH / 64), blk, 0, stream>>>(
      z, ih_hi, ih_lo, b_ih, gi, NSTEPS * BBATCH, G3, NENC, NENC, 0, -1);

  // Phase 2: sequential GRU scan (fp16 weights, 16B packed loads)
  transpose_whh_p8<<<(32 * G3 + 255) / 256, blk, 0, stream>>>(w_hh, wt8);
  scan2_kernel<<<BBATCH, 768, 0, stream>>>(gi, wt8, b_hh, bts);

  // Phase 3: open-loop rollout
  for (int k = 0; k < KWIN; ++k) {
    const float* hin = (k == 0) ? bts : hopen;
    gemm_sbf<<<dim3(G3 / 256, RROWS / 64), blk, 0, stream>>>(
        hin, hhc_hi, hhc_lo, b_hh_c, gbh, RROWS, G3, MHID, MHID, 0, -1);
    open_gates<<<RROWS, 256, 0, stream>>>(gtab, act, gbh, hin, hopen, k);
    gemm_sbf<<<dim3(MHID / 256, RROWS / 64), blk, 0, stream>>>(
        hopen, w1_hi, w1_lo, b1, r1, RROWS, MHID, MHID, MHID, 1, -1);
    gemm_sbf<<<dim3(NENC / 256, RROWS / 64), blk, 0, stream>>>(
        r1, w2_hi, w2_lo, b2, out, RROWS, NENC, MHID, MHID, 0, k);
  }
}

// Round 9
// 1591.656 us; speedup vs baseline: 4.0125x; 1.4183x over previous
//
#include <hip/hip_runtime.h>
#include <hip/hip_fp16.h>
#include <math.h>

// Problem constants
#define TT   240
#define BBATCH 64
#define DDIM 7056
#define KENC_PAD 7072          // 7056 padded to %32
#define NENC 512
#define MHID 256
#define G3   768
#define WRMC 40
#define KWIN 8
#define TOUTC 192
#define RROWS (TOUTC*BBATCH)   // 12288
#define NSTEPS (WRMC + TOUTC)  // 232

// ws layout. float offsets unless BOFF_ (bytes). Lifetime-disjoint (validated r6-r8):
#define OFF_GI    ((size_t)0)
#define OFF_Z     ((size_t)11403264)
#define OFF_HOPEN OFF_Z
#define OFF_WT    OFF_Z                          // scan prologue only; hopen overwrites later
#define OFF_R1    (OFF_Z + (size_t)3145728)
#define OFF_BTS   (OFF_Z + (size_t)7602176)      // 19005440
#define OFF_GBH   OFF_GI
#define BOFF_WENC_HI ((size_t)0)                 // in gi region (dead before gi written)
#define BOFF_WENC_LO ((size_t)7243776)           // 512*7072*2
#define BOFF_WIH_HI  ((size_t)19005440*4)        // bts prefix (dead before scan)
#define BOFF_WIH_LO  (BOFF_WIH_HI + (size_t)786432)
#define BOFF_WHHC_HI ((size_t)(19005440+3276800)*4)  // 89128960
#define BOFF_WHHC_LO (BOFF_WHHC_HI + (size_t)393216)
#define BOFF_W1_HI   (BOFF_WHHC_LO + (size_t)393216)
#define BOFF_W1_LO   (BOFF_W1_HI + (size_t)131072)
#define BOFF_W2_HI   (BOFF_W1_LO + (size_t)131072)
#define BOFF_W2_LO   (BOFF_W2_HI + (size_t)262144)
#define OFF_GTAB  ((size_t)((89128960 + 1572864) / 4))   // 22675456

typedef __attribute__((ext_vector_type(8))) short short8v;
typedef __attribute__((ext_vector_type(4))) float f32x4;
typedef _Float16 h2v __attribute__((ext_vector_type(2)));

__device__ __forceinline__ float sigmf(float x) { return 1.0f / (1.0f + expf(-x)); }
__device__ __forceinline__ unsigned short f2bf(float x) {  // RNE, finite inputs
  unsigned int u = __float_as_uint(x);
  u += 0x7FFFu + ((u >> 16) & 1u);
  return (unsigned short)(u >> 16);
}
__device__ __forceinline__ float bf2f(unsigned short b) {
  return __uint_as_float(((unsigned int)b) << 16);
}
__device__ __forceinline__ h2v u2h2(unsigned int u) {
  union { unsigned int u; h2v h; } c; c.u = u; return c.h;
}

// Split W[N][K] fp32 -> hi/lo bf16 [N][Kpad] (zero-padded)
__global__ void wsplit_kernel(const float* __restrict__ W, short* __restrict__ hi,
                              short* __restrict__ lo, int N, int K, int Kpad) {
  const int idx = blockIdx.x * 256 + threadIdx.x;
  if (idx >= N * Kpad) return;
  const int n = idx / Kpad, k = idx % Kpad;
  const float v = (k < K) ? W[(size_t)n * K + k] : 0.f;
  const unsigned short h = f2bf(v);
  const unsigned short l = f2bf(v - bf2f(h));
  hi[idx] = (short)h; lo[idx] = (short)l;
}

// Split-bf16 MFMA GEMM: C[M,N] = A[M,K]fp32 @ W[N,K]^T (+bias, relu, outk scatter)
// BM=64, BN=256, BK=32; 256 threads (4 waves), wave w owns cols [w*64, w*64+64).
__global__ __launch_bounds__(256, 2) void gemm_sbf(
    const float* __restrict__ A, const short* __restrict__ Whi, const short* __restrict__ Wlo,
    const float* __restrict__ bias, float* __restrict__ C,
    int M, int N, int K, int Kpad, int relu, int outk)
{
  __shared__ short Ah[64][40], Al[64][40];
  __shared__ short Bh[256][40], Bl[256][40];
  const int tid = threadIdx.x;
  const int bx = blockIdx.x, by = blockIdx.y;
  const int w = tid >> 6;
  const int lane = tid & 63;
  const int l15 = lane & 15;
  const int khalf = (lane >> 4) * 8;

  f32x4 acc[4][4];
#pragma unroll
  for (int i = 0; i < 4; ++i)
#pragma unroll
    for (int j = 0; j < 4; ++j) acc[i][j] = (f32x4){0.f, 0.f, 0.f, 0.f};

  for (int k0 = 0; k0 < Kpad; k0 += 32) {
    __syncthreads();
#pragma unroll
    for (int u = 0; u < 2; ++u) {
      const int f = tid + u * 256;
      const int row = f >> 3;
      const int kq = (f & 7) * 4;
      float4 v = make_float4(0.f, 0.f, 0.f, 0.f);
      if (k0 + kq < K)
        v = *(const float4*)(A + (size_t)(by * 64 + row) * K + k0 + kq);
      const float vv[4] = {v.x, v.y, v.z, v.w};
      short h[4], l[4];
#pragma unroll
      for (int i = 0; i < 4; ++i) {
        const unsigned short hb = f2bf(vv[i]);
        h[i] = (short)hb;
        l[i] = (short)f2bf(vv[i] - bf2f(hb));
      }
      *(short4*)&Ah[row][kq] = make_short4(h[0], h[1], h[2], h[3]);
      *(short4*)&Al[row][kq] = make_short4(l[0], l[1], l[2], l[3]);
    }
#pragma unroll
    for (int u = 0; u < 8; ++u) {
      const int f = tid + u * 256;
      const int bufsel = f >> 10;
      const int idx = f & 1023;
      const int n = idx >> 2;
      const int kq8 = (idx & 3) * 8;
      const short* src = (bufsel ? Wlo : Whi) + (size_t)(bx * 256 + n) * Kpad + k0 + kq8;
      const float4 v = *(const float4*)src;
      short* dst = (bufsel ? &Bl[0][0] : &Bh[0][0]) + n * 40 + kq8;
      *(float4*)dst = v;
    }
    __syncthreads();

    short8v ah[4], al[4], bh[4], bl[4];
#pragma unroll
    for (int i = 0; i < 4; ++i) {
      ah[i] = *(short8v*)&Ah[i * 16 + l15][khalf];
      al[i] = *(short8v*)&Al[i * 16 + l15][khalf];
      bh[i] = *(short8v*)&Bh[w * 64 + i * 16 + l15][khalf];
      bl[i] = *(short8v*)&Bl[w * 64 + i * 16 + l15][khalf];
    }
#pragma unroll
    for (int i = 0; i < 4; ++i)
#pragma unroll
      for (int j = 0; j < 4; ++j) {
        acc[i][j] = __builtin_amdgcn_mfma_f32_16x16x32_bf16(ah[i], bh[j], acc[i][j], 0, 0, 0);
        acc[i][j] = __builtin_amdgcn_mfma_f32_16x16x32_bf16(ah[i], bl[j], acc[i][j], 0, 0, 0);
        acc[i][j] = __builtin_amdgcn_mfma_f32_16x16x32_bf16(al[i], bh[j], acc[i][j], 0, 0, 0);
      }
  }

  const int r4 = (lane >> 4) * 4;
#pragma unroll
  for (int j = 0; j < 4; ++j) {
    const int col = bx * 256 + w * 64 + j * 16 + l15;
    const float bc = bias ? bias[col] : 0.f;
#pragma unroll
    for (int i = 0; i < 4; ++i) {
      const int mbase = by * 64 + i * 16 + r4;
#pragma unroll
      for (int r = 0; r < 4; ++r) {
        const int m = mbase + r;
        float vv = acc[i][j][r] + bc;
        if (relu) vv = fmaxf(vv, 0.f);
        float* dst;
        if (outk >= 0) {
          const int t = m >> 6, b = m & 63;
          dst = C + (((size_t)(t * KWIN + outk) * BBATCH + b) * NENC) + col;
        } else {
          dst = C + (size_t)m * N + col;
        }
        *dst = vv;
      }
    }
  }
}

// gi_table[a][c] = emb[a,:] @ w_ih_c[c,:] + b_ih_c[c]   (18 x 768)
__global__ void gitab_kernel(const float* __restrict__ emb, const float* __restrict__ w_ih_c,
                             const float* __restrict__ b_ih_c, float* __restrict__ gt)
{
  const int idx = blockIdx.x * blockDim.x + threadIdx.x;
  if (idx >= 18 * G3) return;
  const int a = idx / G3, cgate = idx % G3;
  float s = b_ih_c[cgate];
#pragma unroll
  for (int e = 0; e < 32; ++e) s = fmaf(emb[a * 32 + e], w_ih_c[cgate * 32 + e], s);
  gt[idx] = s;
}

// wt8 packing: wt8[k8][j] = float4 holding 8 fp16 = w_hh[j][k8*8 .. k8*8+7].
__global__ void transpose_whh_p8(const float* __restrict__ w, float4* __restrict__ wt8) {
  const int id = blockIdx.x * 256 + threadIdx.x;   // 0..24575
  if (id >= 32 * G3) return;
  const int k8 = id / G3, j = id % G3;
  const float* src = w + (size_t)j * MHID + k8 * 8;
  __half2 h2[4];
#pragma unroll
  for (int q = 0; q < 4; ++q)
    h2[q] = __floats2half2_rn(src[2 * q], src[2 * q + 1]);
  wt8[id] = *(float4*)h2;
}

// scan4: register-resident fp16 weights. One block per sample, 768 threads;
// thread j holds gate-row j's 256 fp16 weights in 128 VGPRs. h broadcast from
// LDS as fp16; full dot per thread via v_dot2_f32_f16 -> no shuffle reduce,
// no per-step weight memory traffic at all.
__global__ __launch_bounds__(768, 3) void scan4_kernel(
    const float* __restrict__ gi_all, const float4* __restrict__ wt8,
    const float* __restrict__ b_hh, float* __restrict__ bts)
{
  const int b = blockIdx.x;
  const int j = threadIdx.x;
  __shared__ __align__(16) float hs[256];
  __shared__ __align__(16) __half hs16[256];
  __shared__ float gacc[768];

  // Weight prologue: 256 fp16 (row j) into 128 VGPRs, coalesced 16B loads.
  unsigned int wreg[128];
#pragma unroll
  for (int k8 = 0; k8 < 32; ++k8) {
    const float4 v = wt8[(size_t)k8 * G3 + j];
    const uint4 u = *(const uint4*)&v;
    wreg[k8 * 4 + 0] = u.x; wreg[k8 * 4 + 1] = u.y;
    wreg[k8 * 4 + 2] = u.z; wreg[k8 * 4 + 3] = u.w;
  }
  const float bj = b_hh[j];
  if (j < 256) { hs[j] = 0.f; hs16[j] = __float2half(0.f); }
  __syncthreads();

  const uint4* h16v = (const uint4*)hs16;

  for (int t = 0; t < NSTEPS; ++t) {
    // gi loads issue early; latency hides under the dot loop.
    float gr = 0.f, gz = 0.f, gn = 0.f;
    if (j < 256) {
      const float* gp = gi_all + ((size_t)t * BBATCH + b) * G3;
      gr = gp[j]; gz = gp[256 + j]; gn = gp[512 + j];
    }

    float a0 = bj, a1 = 0.f, a2 = 0.f, a3 = 0.f;
#pragma unroll
    for (int k8 = 0; k8 < 32; ++k8) {
      const uint4 hu = h16v[k8];            // broadcast: 8 fp16 h values
#if __has_builtin(__builtin_amdgcn_fdot2)
      a0 = __builtin_amdgcn_fdot2(u2h2(wreg[k8 * 4 + 0]), u2h2(hu.x), a0, false);
      a1 = __builtin_amdgcn_fdot2(u2h2(wreg[k8 * 4 + 1]), u2h2(hu.y), a1, false);
      a2 = __builtin_amdgcn_fdot2(u2h2(wreg[k8 * 4 + 2]), u2h2(hu.z), a2, false);
      a3 = __builtin_amdgcn_fdot2(u2h2(wreg[k8 * 4 + 3]), u2h2(hu.w), a3, false);
#else
      {
        const h2v w0 = u2h2(wreg[k8 * 4 + 0]), w1 = u2h2(wreg[k8 * 4 + 1]);
        const h2v w2 = u2h2(wreg[k8 * 4 + 2]), w3 = u2h2(wreg[k8 * 4 + 3]);
        const h2v x0 = u2h2(hu.x), x1 = u2h2(hu.y), x2 = u2h2(hu.z), x3 = u2h2(hu.w);
        a0 = fmaf((float)w0.x, (float)x0.x, a0); a0 = fmaf((float)w0.y, (float)x0.y, a0);
        a1 = fmaf((float)w1.x, (float)x1.x, a1); a1 = fmaf((float)w1.y, (float)x1.y, a1);
        a2 = fmaf((float)w2.x, (float)x2.x, a2); a2 = fmaf((float)w2.y, (float)x2.y, a2);
        a3 = fmaf((float)w3.x, (float)x3.x, a3); a3 = fmaf((float)w3.y, (float)x3.y, a3);
      }
#endif
    }
    gacc[j] = (a0 + a1) + (a2 + a3);
    __syncthreads();

    if (j < 256) {
      const float r = sigmf(gr + gacc[j]);
      const float z = sigmf(gz + gacc[256 + j]);
      const float n = tanhf(gn + r * gacc[512 + j]);   // b_hh_n inside r* via acc init
      const float hn = (1.f - z) * n + z * hs[j];
      hs[j] = hn;
      hs16[j] = __float2half(hn);
      if (t >= WRMC) bts[(((size_t)(t - WRMC)) * BBATCH + b) * MHID + j] = hn;
    }
    __syncthreads();
  }
}

// Open-loop gate combine
__global__ __launch_bounds__(256) void open_gates(
    const float* __restrict__ gtab, const int* __restrict__ act_seq,
    const float* __restrict__ gh, const float* __restrict__ hin,
    float* __restrict__ hout, int kstep)
{
  const int row = blockIdx.x;
  const int j = threadIdx.x;
  const int t = row >> 6, b = row & 63;
  const int a = act_seq[(WRMC + t + kstep) * BBATCH + b];
  const float* gi = gtab + a * G3;
  const float gr = gi[j], gz = gi[256 + j], gn = gi[512 + j];
  const size_t g0 = (size_t)row * G3;
  const float hr = gh[g0 + j], hz = gh[g0 + 256 + j], hnn = gh[g0 + 512 + j];
  const float h = hin[(size_t)row * MHID + j];
  const float r = sigmf(gr + hr);
  const float z = sigmf(gz + hz);
  const float n = tanhf(gn + r * hnn);
  hout[(size_t)row * MHID + j] = (1.f - z) * n + z * h;
}

extern "C" void kernel_launch(void* const* d_in, const int* in_sizes, int n_in,
                              void* d_out, int out_size, void* d_ws, size_t ws_size,
                              hipStream_t stream) {
  const float* obs    = (const float*)d_in[0];
  const int*   act    = (const int*)  d_in[1];
  const float* w_enc  = (const float*)d_in[2];
  const float* b_enc  = (const float*)d_in[3];
  const float* w_ih   = (const float*)d_in[4];
  const float* w_hh   = (const float*)d_in[5];
  const float* b_ih   = (const float*)d_in[6];
  const float* b_hh   = (const float*)d_in[7];
  const float* w_ih_c = (const float*)d_in[8];
  const float* w_hh_c = (const float*)d_in[9];
  const float* b_ih_c = (const float*)d_in[10];
  const float* b_hh_c = (const float*)d_in[11];
  const float* W1     = (const float*)d_in[12];
  const float* b1     = (const float*)d_in[13];
  const float* W2     = (const float*)d_in[14];
  const float* b2     = (const float*)d_in[15];
  const float* emb    = (const float*)d_in[16];

  float* ws  = (float*)d_ws;
  char*  wsb = (char*)d_ws;
  float* out = (float*)d_out;

  float* z     = ws + OFF_Z;
  float* gi    = ws + OFF_GI;
  float* bts   = ws + OFF_BTS;
  float* gtab  = ws + OFF_GTAB;
  float* hopen = ws + OFF_HOPEN;
  float* r1    = ws + OFF_R1;
  float4* wt8  = (float4*)(ws + OFF_WT);
  float* gbh   = ws + OFF_GBH;

  short* enc_hi = (short*)(wsb + BOFF_WENC_HI);
  short* enc_lo = (short*)(wsb + BOFF_WENC_LO);
  short* ih_hi  = (short*)(wsb + BOFF_WIH_HI);
  short* ih_lo  = (short*)(wsb + BOFF_WIH_LO);
  short* hhc_hi = (short*)(wsb + BOFF_WHHC_HI);
  short* hhc_lo = (short*)(wsb + BOFF_WHHC_LO);
  short* w1_hi  = (short*)(wsb + BOFF_W1_HI);
  short* w1_lo  = (short*)(wsb + BOFF_W1_LO);
  short* w2_hi  = (short*)(wsb + BOFF_W2_HI);
  short* w2_lo  = (short*)(wsb + BOFF_W2_LO);

  const dim3 blk(256);

  // Weight pre-splits (fp32 -> bf16 hi/lo)
  wsplit_kernel<<<(NENC * KENC_PAD + 255) / 256, blk, 0, stream>>>(w_enc, enc_hi, enc_lo, NENC, DDIM, KENC_PAD);
  wsplit_kernel<<<(G3 * NENC + 255) / 256, blk, 0, stream>>>(w_ih, ih_hi, ih_lo, G3, NENC, NENC);
  wsplit_kernel<<<(G3 * MHID + 255) / 256, blk, 0, stream>>>(w_hh_c, hhc_hi, hhc_lo, G3, MHID, MHID);
  wsplit_kernel<<<(MHID * MHID + 255) / 256, blk, 0, stream>>>(W1, w1_hi, w1_lo, MHID, MHID, MHID);
  wsplit_kernel<<<(NENC * MHID + 255) / 256, blk, 0, stream>>>(W2, w2_hi, w2_lo, NENC, MHID, MHID);
  gitab_kernel<<<54, 256, 0, stream>>>(emb, w_ih_c, b_ih_c, gtab);

  // Phase 1: encoder + input gates (232 steps)
  gemm_sbf<<<dim3(NENC / 256, NSTEPS * BBATCH / 64), blk, 0, stream>>>(
      obs, enc_hi, enc_lo, b_enc, z, NSTEPS * BBATCH, NENC, DDIM, KENC_PAD, 0, -1);
  gemm_sbf<<<dim3(G3 / 256, NSTEPS * BBATCH / 64), blk, 0, stream>>>(
      z, ih_hi, ih_lo, b_ih, gi, NSTEPS * BBATCH, G3, NENC, NENC, 0, -1);

  // Phase 2: sequential GRU scan (register-resident fp16 weights)
  transpose_whh_p8<<<(32 * G3 + 255) / 256, blk, 0, stream>>>(w_hh, wt8);
  scan4_kernel<<<BBATCH, 768, 0, stream>>>(gi, wt8, b_hh, bts);

  // Phase 3: open-loop rollout
  for (int k = 0; k < KWIN; ++k) {
    const float* hin = (k == 0) ? bts : hopen;
    gemm_sbf<<<dim3(G3 / 256, RROWS / 64), blk, 0, stream>>>(
        hin, hhc_hi, hhc_lo, b_hh_c, gbh, RROWS, G3, MHID, MHID, 0, -1);
    open_gates<<<RROWS, 256, 0, stream>>>(gtab, act, gbh, hin, hopen, k);
    gemm_sbf<<<dim3(MHID / 256, RROWS / 64), blk, 0, stream>>>(
        hopen, w1_hi, w1_lo, b1, r1, RROWS, MHID, MHID, MHID, 1, -1);
    gemm_sbf<<<dim3(NENC / 256, RROWS / 64), blk, 0, stream>>>(
        r1, w2_hi, w2_lo, b2, out, RROWS, NENC, MHID, MHID, 0, k);
  }
}

// Round 10
// 1205.904 us; speedup vs baseline: 5.2960x; 1.3199x over previous
//
#include <hip/hip_runtime.h>
#include <hip/hip_fp16.h>
#include <math.h>

// Problem constants
#define TT   240
#define BBATCH 64
#define DDIM 7056
#define KENC_PAD 7072          // 7056 padded to %32
#define NENC 512
#define MHID 256
#define G3   768
#define WRMC 40
#define KWIN 8
#define TOUTC 192
#define RROWS (TOUTC*BBATCH)   // 12288
#define NSTEPS (WRMC + TOUTC)  // 232

// ws layout (BYTE offsets). Lifetime-disjoint; peak 88.0 MB <= 91.8 validated.
//  [0,45.6M): gi (P1b..P2). Overlays: w_enc_h (P0..P1a), gbh+r1_h (P3).
//  [45.6,60.8M): z_h (P1a..P1b). Overlay: hopen fp32 (P3).
//  [60.8,73.4M): bts fp32.  [73.4,79.7M): bts_h.  [79.7,86.0M): hopen_h.
//  [86.0,88.0M): persistent smalls (w_ih_h, w_hhc_h, W1_h, W2_h, gtab, wt8).
#define B_GI     ((size_t)0)
#define B_WENCH  ((size_t)0)
#define B_GBH    ((size_t)0)
#define B_R1H    ((size_t)37748736)
#define B_ZH     ((size_t)45613056)
#define B_HOPEN  ((size_t)45613056)
#define B_BTS    ((size_t)60817408)
#define B_BTSH   ((size_t)73400320)
#define B_HOPENH ((size_t)79691776)
#define B_WIHH   ((size_t)85983232)
#define B_WHHCH  ((size_t)86769664)
#define B_W1H    ((size_t)87162880)
#define B_W2H    ((size_t)87293952)
#define B_GTAB   ((size_t)87556096)
#define B_WT8    ((size_t)87611392)

typedef _Float16 half8 __attribute__((ext_vector_type(8)));
typedef _Float16 h2v  __attribute__((ext_vector_type(2)));
typedef __attribute__((ext_vector_type(4))) float f32x4;

__device__ __forceinline__ float sigmf(float x) { return 1.0f / (1.0f + expf(-x)); }
__device__ __forceinline__ h2v u2h2(unsigned int u) {
  union { unsigned int u; h2v h; } c; c.u = u; return c.h;
}

// W[N][K] fp32 -> fp16 [N][Kpad] (zero-padded)
__global__ void wconv_kernel(const float* __restrict__ W, __half* __restrict__ o,
                             int N, int K, int Kpad) {
  const int idx = blockIdx.x * 256 + threadIdx.x;
  if (idx >= N * Kpad) return;
  const int n = idx / Kpad, k = idx % Kpad;
  o[idx] = __float2half((k < K) ? W[(size_t)n * K + k] : 0.f);
}

// fp16 MFMA GEMM: C[M,N] = A[M,K] @ W[N,K]^T + bias (relu / fp16-out / outk-scatter)
// A either fp32 (converted in staging) or fp16. BM=64, BN=256, BK=32, 4 waves.
__global__ __launch_bounds__(256, 4) void gemm_h(
    const void* __restrict__ A, int a_fp32, const __half* __restrict__ W,
    const float* __restrict__ bias, void* __restrict__ C,
    int M, int N, int K, int Kpad, int relu, int out_h, int outk)
{
  __shared__ __half Ah[64][40];
  __shared__ __half Bh[256][40];
  const int tid = threadIdx.x;
  const int bx = blockIdx.x, by = blockIdx.y;
  const int w = tid >> 6;
  const int lane = tid & 63;
  const int l15 = lane & 15;
  const int khalf = (lane >> 4) * 8;

  f32x4 acc[4][4];
#pragma unroll
  for (int i = 0; i < 4; ++i)
#pragma unroll
    for (int j = 0; j < 4; ++j) acc[i][j] = (f32x4){0.f, 0.f, 0.f, 0.f};

  const int arow = tid >> 2;
  const int akq = (tid & 3) * 8;

  for (int k0 = 0; k0 < Kpad; k0 += 32) {
    __syncthreads();
    // stage A tile 64x32
    if (a_fp32) {
      const float* Af = (const float*)A;
      float4 v0 = make_float4(0.f, 0.f, 0.f, 0.f);
      float4 v1 = make_float4(0.f, 0.f, 0.f, 0.f);
      const size_t base = (size_t)(by * 64 + arow) * K + k0 + akq;
      if (k0 + akq < K)     v0 = *(const float4*)(Af + base);
      if (k0 + akq + 4 < K) v1 = *(const float4*)(Af + base + 4);
      __half2 hh[4];
      hh[0] = __floats2half2_rn(v0.x, v0.y);
      hh[1] = __floats2half2_rn(v0.z, v0.w);
      hh[2] = __floats2half2_rn(v1.x, v1.y);
      hh[3] = __floats2half2_rn(v1.z, v1.w);
      *(float4*)&Ah[arow][akq] = *(float4*)hh;
    } else {
      const __half* Ahp = (const __half*)A;
      *(float4*)&Ah[arow][akq] =
          *(const float4*)(Ahp + (size_t)(by * 64 + arow) * Kpad + k0 + akq);
    }
    // stage B tile 256x32
#pragma unroll
    for (int u = 0; u < 4; ++u) {
      const int f = tid + u * 256;
      const int n = f >> 2;
      const int kq8 = (f & 3) * 8;
      *(float4*)&Bh[n][kq8] =
          *(const float4*)(W + (size_t)(bx * 256 + n) * Kpad + k0 + kq8);
    }
    __syncthreads();

    half8 ah[4], bh[4];
#pragma unroll
    for (int i = 0; i < 4; ++i) {
      ah[i] = *(half8*)&Ah[i * 16 + l15][khalf];
      bh[i] = *(half8*)&Bh[w * 64 + i * 16 + l15][khalf];
    }
#pragma unroll
    for (int i = 0; i < 4; ++i)
#pragma unroll
      for (int j = 0; j < 4; ++j)
        acc[i][j] = __builtin_amdgcn_mfma_f32_16x16x32_f16(ah[i], bh[j], acc[i][j], 0, 0, 0);
  }

  // epilogue: row = by*64 + i*16 + (lane>>4)*4 + r ; col = bx*256 + w*64 + j*16 + l15
  const int r4 = (lane >> 4) * 4;
#pragma unroll
  for (int j = 0; j < 4; ++j) {
    const int col = bx * 256 + w * 64 + j * 16 + l15;
    const float bc = bias ? bias[col] : 0.f;
#pragma unroll
    for (int i = 0; i < 4; ++i) {
      const int mbase = by * 64 + i * 16 + r4;
#pragma unroll
      for (int r = 0; r < 4; ++r) {
        const int m = mbase + r;
        float vv = acc[i][j][r] + bc;
        if (relu) vv = fmaxf(vv, 0.f);
        if (outk >= 0) {
          const int t = m >> 6, b = m & 63;
          ((float*)C)[(((size_t)(t * KWIN + outk) * BBATCH + b) * NENC) + col] = vv;
        } else if (out_h) {
          ((__half*)C)[(size_t)m * N + col] = __float2half(vv);
        } else {
          ((float*)C)[(size_t)m * N + col] = vv;
        }
      }
    }
  }
}

// gi_table[a][c] = emb[a,:] @ w_ih_c[c,:] + b_ih_c[c]   (18 x 768)
__global__ void gitab_kernel(const float* __restrict__ emb, const float* __restrict__ w_ih_c,
                             const float* __restrict__ b_ih_c, float* __restrict__ gt)
{
  const int idx = blockIdx.x * blockDim.x + threadIdx.x;
  if (idx >= 18 * G3) return;
  const int a = idx / G3, cgate = idx % G3;
  float s = b_ih_c[cgate];
#pragma unroll
  for (int e = 0; e < 32; ++e) s = fmaf(emb[a * 32 + e], w_ih_c[cgate * 32 + e], s);
  gt[idx] = s;
}

// wt8 packing: wt8[k8][j] = float4 holding 8 fp16 = w_hh[j][k8*8 .. k8*8+7].
__global__ void transpose_whh_p8(const float* __restrict__ w, float4* __restrict__ wt8) {
  const int id = blockIdx.x * 256 + threadIdx.x;
  if (id >= 32 * G3) return;
  const int k8 = id / G3, j = id % G3;
  const float* src = w + (size_t)j * MHID + k8 * 8;
  __half2 h2[4];
#pragma unroll
  for (int q = 0; q < 4; ++q)
    h2[q] = __floats2half2_rn(src[2 * q], src[2 * q + 1]);
  wt8[id] = *(float4*)h2;
}

// scan4: register-resident fp16 weights (validated round 9); adds bts_h fp16 write.
__global__ __launch_bounds__(768, 3) void scan4_kernel(
    const float* __restrict__ gi_all, const float4* __restrict__ wt8,
    const float* __restrict__ b_hh, float* __restrict__ bts,
    __half* __restrict__ bts_h)
{
  const int b = blockIdx.x;
  const int j = threadIdx.x;
  __shared__ __align__(16) float hs[256];
  __shared__ __align__(16) __half hs16[256];
  __shared__ float gacc[768];

  unsigned int wreg[128];
#pragma unroll
  for (int k8 = 0; k8 < 32; ++k8) {
    const float4 v = wt8[(size_t)k8 * G3 + j];
    const uint4 u = *(const uint4*)&v;
    wreg[k8 * 4 + 0] = u.x; wreg[k8 * 4 + 1] = u.y;
    wreg[k8 * 4 + 2] = u.z; wreg[k8 * 4 + 3] = u.w;
  }
  const float bj = b_hh[j];
  if (j < 256) { hs[j] = 0.f; hs16[j] = __float2half(0.f); }
  __syncthreads();

  const uint4* h16v = (const uint4*)hs16;

  for (int t = 0; t < NSTEPS; ++t) {
    float gr = 0.f, gz = 0.f, gn = 0.f;
    if (j < 256) {
      const float* gp = gi_all + ((size_t)t * BBATCH + b) * G3;
      gr = gp[j]; gz = gp[256 + j]; gn = gp[512 + j];
    }

    float a0 = bj, a1 = 0.f, a2 = 0.f, a3 = 0.f;
#pragma unroll
    for (int k8 = 0; k8 < 32; ++k8) {
      const uint4 hu = h16v[k8];
#if __has_builtin(__builtin_amdgcn_fdot2)
      a0 = __builtin_amdgcn_fdot2(u2h2(wreg[k8 * 4 + 0]), u2h2(hu.x), a0, false);
      a1 = __builtin_amdgcn_fdot2(u2h2(wreg[k8 * 4 + 1]), u2h2(hu.y), a1, false);
      a2 = __builtin_amdgcn_fdot2(u2h2(wreg[k8 * 4 + 2]), u2h2(hu.z), a2, false);
      a3 = __builtin_amdgcn_fdot2(u2h2(wreg[k8 * 4 + 3]), u2h2(hu.w), a3, false);
#else
      {
        const h2v w0 = u2h2(wreg[k8 * 4 + 0]), w1 = u2h2(wreg[k8 * 4 + 1]);
        const h2v w2 = u2h2(wreg[k8 * 4 + 2]), w3 = u2h2(wreg[k8 * 4 + 3]);
        const h2v x0 = u2h2(hu.x), x1 = u2h2(hu.y), x2 = u2h2(hu.z), x3 = u2h2(hu.w);
        a0 = fmaf((float)w0.x, (float)x0.x, a0); a0 = fmaf((float)w0.y, (float)x0.y, a0);
        a1 = fmaf((float)w1.x, (float)x1.x, a1); a1 = fmaf((float)w1.y, (float)x1.y, a1);
        a2 = fmaf((float)w2.x, (float)x2.x, a2); a2 = fmaf((float)w2.y, (float)x2.y, a2);
        a3 = fmaf((float)w3.x, (float)x3.x, a3); a3 = fmaf((float)w3.y, (float)x3.y, a3);
      }
#endif
    }
    gacc[j] = (a0 + a1) + (a2 + a3);
    __syncthreads();

    if (j < 256) {
      const float r = sigmf(gr + gacc[j]);
      const float z = sigmf(gz + gacc[256 + j]);
      const float n = tanhf(gn + r * gacc[512 + j]);   // b_hh_n inside r* via acc init
      const float hn = (1.f - z) * n + z * hs[j];
      hs[j] = hn;
      hs16[j] = __float2half(hn);
      if (t >= WRMC) {
        const size_t o = (((size_t)(t - WRMC)) * BBATCH + b) * MHID + j;
        bts[o] = hn;
        bts_h[o] = __float2half(hn);
      }
    }
    __syncthreads();
  }
}

// Open-loop gate combine; writes h' as fp32 (state) and fp16 (next GEMM's A)
__global__ __launch_bounds__(256) void open_gates(
    const float* __restrict__ gtab, const int* __restrict__ act_seq,
    const float* __restrict__ gh, const float* __restrict__ hin,
    float* __restrict__ hout, __half* __restrict__ hout_h, int kstep)
{
  const int row = blockIdx.x;
  const int j = threadIdx.x;
  const int t = row >> 6, b = row & 63;
  const int a = act_seq[(WRMC + t + kstep) * BBATCH + b];
  const float* gi = gtab + a * G3;
  const float gr = gi[j], gz = gi[256 + j], gn = gi[512 + j];
  const size_t g0 = (size_t)row * G3;
  const float hr = gh[g0 + j], hz = gh[g0 + 256 + j], hnn = gh[g0 + 512 + j];
  const float h = hin[(size_t)row * MHID + j];
  const float r = sigmf(gr + hr);
  const float z = sigmf(gz + hz);
  const float n = tanhf(gn + r * hnn);
  const float hn = (1.f - z) * n + z * h;
  hout[(size_t)row * MHID + j] = hn;
  hout_h[(size_t)row * MHID + j] = __float2half(hn);
}

extern "C" void kernel_launch(void* const* d_in, const int* in_sizes, int n_in,
                              void* d_out, int out_size, void* d_ws, size_t ws_size,
                              hipStream_t stream) {
  const float* obs    = (const float*)d_in[0];
  const int*   act    = (const int*)  d_in[1];
  const float* w_enc  = (const float*)d_in[2];
  const float* b_enc  = (const float*)d_in[3];
  const float* w_ih   = (const float*)d_in[4];
  const float* w_hh   = (const float*)d_in[5];
  const float* b_ih   = (const float*)d_in[6];
  const float* b_hh   = (const float*)d_in[7];
  const float* w_ih_c = (const float*)d_in[8];
  const float* w_hh_c = (const float*)d_in[9];
  const float* b_ih_c = (const float*)d_in[10];
  const float* b_hh_c = (const float*)d_in[11];
  const float* W1     = (const float*)d_in[12];
  const float* b1     = (const float*)d_in[13];
  const float* W2     = (const float*)d_in[14];
  const float* b2     = (const float*)d_in[15];
  const float* emb    = (const float*)d_in[16];

  char* wsb = (char*)d_ws;
  float* out = (float*)d_out;

  float*  gi      = (float*)(wsb + B_GI);
  float*  gbh     = (float*)(wsb + B_GBH);
  __half* r1_h    = (__half*)(wsb + B_R1H);
  __half* z_h     = (__half*)(wsb + B_ZH);
  float*  hopen   = (float*)(wsb + B_HOPEN);
  float*  bts     = (float*)(wsb + B_BTS);
  __half* bts_h   = (__half*)(wsb + B_BTSH);
  __half* hopen_h = (__half*)(wsb + B_HOPENH);
  __half* enc_h   = (__half*)(wsb + B_WENCH);
  __half* ih_h    = (__half*)(wsb + B_WIHH);
  __half* hhc_h   = (__half*)(wsb + B_WHHCH);
  __half* w1_h    = (__half*)(wsb + B_W1H);
  __half* w2_h    = (__half*)(wsb + B_W2H);
  float*  gtab    = (float*)(wsb + B_GTAB);
  float4* wt8     = (float4*)(wsb + B_WT8);

  const dim3 blk(256);

  // Weight fp16 conversions + small tables
  wconv_kernel<<<(NENC * KENC_PAD + 255) / 256, blk, 0, stream>>>(w_enc, enc_h, NENC, DDIM, KENC_PAD);
  wconv_kernel<<<(G3 * NENC + 255) / 256, blk, 0, stream>>>(w_ih, ih_h, G3, NENC, NENC);
  wconv_kernel<<<(G3 * MHID + 255) / 256, blk, 0, stream>>>(w_hh_c, hhc_h, G3, MHID, MHID);
  wconv_kernel<<<(MHID * MHID + 255) / 256, blk, 0, stream>>>(W1, w1_h, MHID, MHID, MHID);
  wconv_kernel<<<(NENC * MHID + 255) / 256, blk, 0, stream>>>(W2, w2_h, NENC, MHID, MHID);
  gitab_kernel<<<54, 256, 0, stream>>>(emb, w_ih_c, b_ih_c, gtab);
  transpose_whh_p8<<<(32 * G3 + 255) / 256, blk, 0, stream>>>(w_hh, wt8);

  // Phase 1: encoder (fp32 A, in-staging cvt; fp16 z out) + input gates
  gemm_h<<<dim3(NENC / 256, NSTEPS * BBATCH / 64), blk, 0, stream>>>(
      obs, 1, enc_h, b_enc, z_h, NSTEPS * BBATCH, NENC, DDIM, KENC_PAD, 0, 1, -1);
  gemm_h<<<dim3(G3 / 256, NSTEPS * BBATCH / 64), blk, 0, stream>>>(
      z_h, 0, ih_h, b_ih, gi, NSTEPS * BBATCH, G3, NENC, NENC, 0, 0, -1);

  // Phase 2: sequential GRU scan (register-resident fp16 weights)
  scan4_kernel<<<BBATCH, 768, 0, stream>>>(gi, wt8, b_hh, bts, bts_h);

  // Phase 3: open-loop rollout
  for (int k = 0; k < KWIN; ++k) {
    const __half* hin_h = (k == 0) ? bts_h : hopen_h;
    const float*  hin   = (k == 0) ? bts   : hopen;
    gemm_h<<<dim3(G3 / 256, RROWS / 64), blk, 0, stream>>>(
        hin_h, 0, hhc_h, b_hh_c, gbh, RROWS, G3, MHID, MHID, 0, 0, -1);
    open_gates<<<RROWS, 256, 0, stream>>>(gtab, act, gbh, hin, hopen, hopen_h, k);
    gemm_h<<<dim3(MHID / 256, RROWS / 64), blk, 0, stream>>>(
        hopen_h, 0, w1_h, b1, r1_h, RROWS, MHID, MHID, MHID, 1, 1, -1);
    gemm_h<<<dim3(NENC / 256, RROWS / 64), blk, 0, stream>>>(
        r1_h, 0, w2_h, b2, out, RROWS, NENC, MHID, MHID, 0, 0, k);
  }
}